// Round 1
// baseline (3421.683 us; speedup 1.0000x reference)
//
#include <hip/hip_runtime.h>
#include <hip/hip_bf16.h>

#define N_NODES   50000
#define N_USERS   20000
#define N_EDGES   800000
#define DIM       256
#define NHEAD     8
#define DKH       32

// ---------------- GEMM: C[M,256] = A[M,256] @ W[256,256]^T + b ----------------
// A row r fetched from Alo if r<split else Ahi[r-split] (handles concat(user,item)).
// 128x128 block tile, 256 threads, 8x8 thread tile, KC=32, fp32 vector FMA.
__global__ __launch_bounds__(256) void gemm256_kernel(
    const float* __restrict__ Alo, const float* __restrict__ Ahi, int split,
    const float* __restrict__ W, const float* __restrict__ bias,
    float* __restrict__ C, int M)
{
    __shared__ float4 Asm[8][130];   // [kq][row], pad 130 to spread banks
    __shared__ float4 Wsm[8][130];   // [kq][col]
    const int tid = threadIdx.x;
    const int tx = tid & 15, ty = tid >> 4;
    const int row0 = blockIdx.x * 128;
    const int c0   = blockIdx.y * 128;

    float acc[8][8];
    #pragma unroll
    for (int i = 0; i < 8; ++i)
        #pragma unroll
        for (int j = 0; j < 8; ++j) acc[i][j] = 0.f;

    for (int k0 = 0; k0 < 256; k0 += 32) {
        // stage A[128][32] and W[128][32] as float4 along k
        #pragma unroll
        for (int t = 0; t < 4; ++t) {
            int idx = t * 256 + tid;
            int r = idx >> 3, kq = idx & 7;
            int gr = row0 + r;
            float4 av = make_float4(0.f, 0.f, 0.f, 0.f);
            if (gr < M) {
                const float* Ap = (gr < split) ? (Alo + (size_t)gr * DIM)
                                               : (Ahi + (size_t)(gr - split) * DIM);
                av = *(const float4*)(Ap + k0 + kq * 4);
            }
            Asm[kq][r] = av;
            int gc = c0 + r;                      // always < 256
            Wsm[kq][r] = *(const float4*)(W + (size_t)gc * DIM + k0 + kq * 4);
        }
        __syncthreads();
        #pragma unroll
        for (int kq = 0; kq < 8; ++kq) {
            float4 a[8], w[8];
            #pragma unroll
            for (int i = 0; i < 8; ++i) a[i] = Asm[kq][ty + 16 * i];  // cyclic rows: no bank conflict
            #pragma unroll
            for (int j = 0; j < 8; ++j) w[j] = Wsm[kq][tx + 16 * j];
            #pragma unroll
            for (int i = 0; i < 8; ++i)
                #pragma unroll
                for (int j = 0; j < 8; ++j)
                    acc[i][j] += a[i].x * w[j].x + a[i].y * w[j].y
                               + a[i].z * w[j].z + a[i].w * w[j].w;
        }
        __syncthreads();
    }
    #pragma unroll
    for (int i = 0; i < 8; ++i) {
        int gr = row0 + ty + 16 * i;
        if (gr >= M) continue;
        #pragma unroll
        for (int j = 0; j < 8; ++j) {
            int gc = c0 + tx + 16 * j;
            C[(size_t)gr * DIM + gc] = acc[i][j] + bias[gc];
        }
    }
}

// ---------------- CSR build ----------------
__global__ void hist_kernel(const int* __restrict__ col, int* __restrict__ cnt) {
    int e = blockIdx.x * blockDim.x + threadIdx.x;
    if (e < N_EDGES) atomicAdd(&cnt[col[e]], 1);
}

// single-block exclusive scan over 50000 counts; cnt becomes the scatter cursor
__global__ __launch_bounds__(1024) void scan_kernel(int* __restrict__ cnt, int* __restrict__ offs) {
    __shared__ int sums[1024];
    const int t = threadIdx.x;
    const int chunk = (N_NODES + 1023) >> 10;  // 49
    const int base = t * chunk;
    int s = 0;
    for (int i = 0; i < chunk; ++i) {
        int idx = base + i;
        if (idx < N_NODES) s += cnt[idx];
    }
    sums[t] = s;
    __syncthreads();
    for (int d = 1; d < 1024; d <<= 1) {
        int v = (t >= d) ? sums[t - d] : 0;
        __syncthreads();
        sums[t] += v;
        __syncthreads();
    }
    int run = (t == 0) ? 0 : sums[t - 1];
    for (int i = 0; i < chunk; ++i) {
        int idx = base + i;
        if (idx < N_NODES) {
            int v = cnt[idx];
            offs[idx] = run;
            cnt[idx] = run;     // cursor init
            run += v;
        }
    }
    if (t == 1023) offs[N_NODES] = sums[1023];
}

__global__ void scatter_kernel(const int* __restrict__ row, const int* __restrict__ col,
                               int* __restrict__ cursor,
                               int* __restrict__ eidx, int* __restrict__ esrc) {
    int e = blockIdx.x * blockDim.x + threadIdx.x;
    if (e >= N_EDGES) return;
    int c = col[e];
    int p = atomicAdd(&cursor[c], 1);
    eidx[p] = e;
    esrc[p] = row[e];
}

// ---------------- edge scores: one thread per (edge, head) ----------------
__global__ void scores_kernel(const float* __restrict__ Q, const float* __restrict__ K,
                              const float* __restrict__ rel,
                              const int* __restrict__ row, const int* __restrict__ col,
                              float* __restrict__ scores) {
    int gid = blockIdx.x * blockDim.x + threadIdx.x;
    if (gid >= N_EDGES * NHEAD) return;
    int e = gid >> 3, h = gid & 7;
    int c = col[e], r = row[e];
    const float4* q4 = (const float4*)(Q + (size_t)c * DIM + h * DKH);
    const float4* k4 = (const float4*)(K + (size_t)r * DIM + h * DKH);
    const float4* r4 = (const float4*)(rel + h * DKH);
    float s = 0.f;
    #pragma unroll
    for (int i = 0; i < 8; ++i) {
        float4 q = q4[i], k = k4[i], rr = r4[i];
        s += q.x * (k.x + rr.x) + q.y * (k.y + rr.y)
           + q.z * (k.z + rr.z) + q.w * (k.w + rr.w);
    }
    scores[gid] = s * 0.17677669529663687f;  // 1/sqrt(32)
}

// ---------------- per-node segment softmax + V aggregation: one wave per node ----------------
__global__ __launch_bounds__(256) void node_kernel(
    const float* __restrict__ scores, const float* __restrict__ V,
    const int* __restrict__ offs, const int* __restrict__ eidx, const int* __restrict__ esrc,
    float* __restrict__ out_agg)
{
    int wid = (blockIdx.x * blockDim.x + threadIdx.x) >> 6;
    int lane = threadIdx.x & 63;
    if (wid >= N_NODES) return;
    int beg = offs[wid], end = offs[wid + 1];
    int h = lane >> 3, sub = lane & 7;       // lane owns dims [lane*4, lane*4+4) -> head lane>>3

    float m = -1e30f;
    for (int j = beg + sub; j < end; j += 8)
        m = fmaxf(m, scores[(size_t)eidx[j] * NHEAD + h]);
    m = fmaxf(m, __shfl_xor(m, 1));
    m = fmaxf(m, __shfl_xor(m, 2));
    m = fmaxf(m, __shfl_xor(m, 4));

    float den = 0.f;
    for (int j = beg + sub; j < end; j += 8)
        den += __expf(scores[(size_t)eidx[j] * NHEAD + h] - m);
    den += __shfl_xor(den, 1);
    den += __shfl_xor(den, 2);
    den += __shfl_xor(den, 4);
    float rden = (end > beg) ? 1.f / den : 0.f;

    float4 acc = make_float4(0.f, 0.f, 0.f, 0.f);
    int d0 = lane * 4;
    for (int j = beg; j < end; ++j) {
        int r = esrc[j];
        float w = __expf(scores[(size_t)eidx[j] * NHEAD + h] - m) * rden;
        float4 v = *(const float4*)(V + (size_t)r * DIM + d0);
        acc.x += w * v.x; acc.y += w * v.y; acc.z += w * v.z; acc.w += w * v.w;
    }
    *(float4*)(out_agg + (size_t)wid * DIM + d0) = acc;
}

extern "C" void kernel_launch(void* const* d_in, const int* in_sizes, int n_in,
                              void* d_out, int out_size, void* d_ws, size_t ws_size,
                              hipStream_t stream) {
    const float* x    = (const float*)d_in[0];
    const int*   row  = (const int*)d_in[1];
    const int*   col  = (const int*)d_in[2];
    const float* rel  = (const float*)d_in[3];
    const float* user = (const float*)d_in[4];
    const float* item = (const float*)d_in[5];
    const float* Wq   = (const float*)d_in[6];
    const float* bq   = (const float*)d_in[7];
    const float* Wk   = (const float*)d_in[8];
    const float* bk   = (const float*)d_in[9];
    const float* Wv   = (const float*)d_in[10];
    const float* bv   = (const float*)d_in[11];
    const float* Wo   = (const float*)d_in[12];
    const float* bo   = (const float*)d_in[13];

    char* ws = (char*)d_ws;
    size_t off = 0;
    auto alloc = [&](size_t bytes) -> void* {
        void* p = ws + off;
        off = (off + bytes + 255) & ~(size_t)255;
        return p;
    };
    float* Q       = (float*)alloc((size_t)N_NODES * DIM * 4);
    float* K       = (float*)alloc((size_t)N_NODES * DIM * 4);
    float* V       = (float*)alloc((size_t)N_NODES * DIM * 4);
    float* out_agg = (float*)alloc((size_t)N_NODES * DIM * 4);
    float* scores  = (float*)alloc((size_t)N_EDGES * NHEAD * 4);
    int*   cnt     = (int*)alloc((size_t)N_NODES * 4);
    int*   offs    = (int*)alloc((size_t)(N_NODES + 1) * 4);
    int*   eidx    = (int*)alloc((size_t)N_EDGES * 4);
    int*   esrc    = (int*)alloc((size_t)N_EDGES * 4);

    hipMemsetAsync(cnt, 0, (size_t)N_NODES * 4, stream);

    dim3 gg((N_NODES + 127) / 128, 2);
    // Q = text @ Wq^T + bq ; K = text @ Wk^T + bk ; V = x @ Wv^T + bv
    gemm256_kernel<<<gg, 256, 0, stream>>>(user, item, N_USERS, Wq, bq, Q, N_NODES);
    gemm256_kernel<<<gg, 256, 0, stream>>>(user, item, N_USERS, Wk, bk, K, N_NODES);
    gemm256_kernel<<<gg, 256, 0, stream>>>(x, x, N_NODES, Wv, bv, V, N_NODES);

    hist_kernel<<<(N_EDGES + 255) / 256, 256, 0, stream>>>(col, cnt);
    scan_kernel<<<1, 1024, 0, stream>>>(cnt, offs);
    scatter_kernel<<<(N_EDGES + 255) / 256, 256, 0, stream>>>(row, col, cnt, eidx, esrc);

    scores_kernel<<<(N_EDGES * NHEAD + 255) / 256, 256, 0, stream>>>(Q, K, rel, row, col, scores);
    node_kernel<<<(N_NODES * 64 + 255) / 256, 256, 0, stream>>>(scores, V, offs, eidx, esrc, out_agg);

    // final: d_out = out_agg @ Wo^T + bo
    gemm256_kernel<<<gg, 256, 0, stream>>>(out_agg, out_agg, N_NODES, Wo, bo, (float*)d_out, N_NODES);
}

// Round 2
// 819.696 us; speedup vs baseline: 4.1743x; 4.1743x over previous
//
#include <hip/hip_runtime.h>
#include <hip/hip_bf16.h>

#define N_NODES   50000
#define N_USERS   20000
#define N_EDGES   800000
#define DIM       256
#define NHEAD     8
#define DKH       32

typedef __attribute__((ext_vector_type(8))) short bf16x8;
typedef __attribute__((ext_vector_type(4))) float f32x4;
typedef __attribute__((ext_vector_type(4))) unsigned short u16x4;

__device__ inline unsigned short f2bf(float f) {
    union { __hip_bfloat16 b; unsigned short u; } cv;
    cv.b = __float2bfloat16(f);
    return cv.u;
}

// ---------------- input casts: fp32 -> bf16 ----------------
__global__ void cast_inputs_kernel(const float* __restrict__ x,
                                   const float* __restrict__ user,
                                   const float* __restrict__ item,
                                   unsigned short* __restrict__ xb,
                                   unsigned short* __restrict__ tb)
{
    int gid = blockIdx.x * blockDim.x + threadIdx.x;
    const int total4 = N_NODES * DIM / 4;   // 3.2M float4 groups
    if (gid >= total4) return;
    size_t e = (size_t)gid * 4;
    float4 xv = *(const float4*)(x + e);
    u16x4 xo = { f2bf(xv.x), f2bf(xv.y), f2bf(xv.z), f2bf(xv.w) };
    *(u16x4*)(xb + e) = xo;
    const size_t usplit = (size_t)N_USERS * DIM;   // multiple of 4
    const float* tsrc = (e < usplit) ? (user + e) : (item + (e - usplit));
    float4 tv = *(const float4*)tsrc;
    u16x4 to = { f2bf(tv.x), f2bf(tv.y), f2bf(tv.z), f2bf(tv.w) };
    *(u16x4*)(tb + e) = to;
}

__global__ void cast_w_kernel(const float* __restrict__ Wq, const float* __restrict__ Wk,
                              const float* __restrict__ Wv, const float* __restrict__ Wo,
                              unsigned short* __restrict__ Wb)
{
    int gid = blockIdx.x * blockDim.x + threadIdx.x;   // 65536 threads, 4 elems each
    if (gid >= 65536) return;
    const float* srcs[4] = { Wq, Wk, Wv, Wo };
    int m = gid >> 14;
    int off = (gid & 16383) * 4;
    float4 v = *(const float4*)(srcs[m] + off);
    u16x4 o = { f2bf(v.x), f2bf(v.y), f2bf(v.z), f2bf(v.w) };
    *(u16x4*)(Wb + (size_t)m * 65536 + off) = o;
}

// ---------------- MFMA GEMM: C[M,256] = A[M,256](bf16) @ W[256,256]^T(bf16) + b ----------------
// 128x128 tile, full K=256 staged in LDS (64KB+64KB), XOR-swizzled via pre-swizzled
// global source + linear global_load_lds dest (both-sides involution, rule 21).
__global__ __launch_bounds__(256) void gemm_mfma_kernel(
    const unsigned short* __restrict__ A,   // [M,256] bf16
    const unsigned short* __restrict__ W,   // [256,256] bf16, row n contiguous in k
    const float* __restrict__ bias,
    float* __restrict__ C, int M)
{
    __shared__ unsigned short Asm[128 * 256];   // row stride 512 B
    __shared__ unsigned short Wsm[128 * 256];
    const int tid = threadIdx.x;
    const int lane = tid & 63, wid = tid >> 6;
    const int row0 = blockIdx.x * 128;
    const int col0 = blockIdx.y * 128;

    // stage: 16 iters x (64 lanes x 16B) per wave, 4 waves cover 4KB/iter each array
    #pragma unroll
    for (int it = 0; it < 16; ++it) {
        int o = it * 4096 + tid * 16;             // linear byte offset in tile
        int r = o >> 9;                           // tile row
        int cb = (o & 511) ^ ((r & 7) << 4);      // inverse-swizzled source column byte
        int ga = row0 + r; if (ga >= M) ga = M - 1;
        const char* srcA = (const char*)A + ((size_t)ga << 9) + cb;
        __builtin_amdgcn_global_load_lds(
            (const __attribute__((address_space(1))) unsigned int*)srcA,
            (__attribute__((address_space(3))) unsigned int*)((char*)Asm + it * 4096 + wid * 1024),
            16, 0, 0);
        const char* srcW = (const char*)W + ((size_t)(col0 + r) << 9) + cb;
        __builtin_amdgcn_global_load_lds(
            (const __attribute__((address_space(1))) unsigned int*)srcW,
            (__attribute__((address_space(3))) unsigned int*)((char*)Wsm + it * 4096 + wid * 1024),
            16, 0, 0);
    }
    __syncthreads();

    const int wm = wid >> 1, wn = wid & 1;        // 2x2 wave grid, 64x64 per wave
    const int lr = lane & 15, lk = lane >> 4;
    f32x4 acc[4][4];
    #pragma unroll
    for (int i = 0; i < 4; ++i)
        #pragma unroll
        for (int j = 0; j < 4; ++j) acc[i][j] = (f32x4){0.f, 0.f, 0.f, 0.f};

    #pragma unroll
    for (int ks = 0; ks < 8; ++ks) {
        bf16x8 a[4], b[4];
        #pragma unroll
        for (int i = 0; i < 4; ++i) {
            int r = wm * 64 + i * 16 + lr;
            int cb = (ks * 64 + lk * 16) ^ ((r & 7) << 4);
            a[i] = *(const bf16x8*)((const char*)Asm + r * 512 + cb);
        }
        #pragma unroll
        for (int j = 0; j < 4; ++j) {
            int r = wn * 64 + j * 16 + lr;
            int cb = (ks * 64 + lk * 16) ^ ((r & 7) << 4);
            b[j] = *(const bf16x8*)((const char*)Wsm + r * 512 + cb);
        }
        #pragma unroll
        for (int i = 0; i < 4; ++i)
            #pragma unroll
            for (int j = 0; j < 4; ++j)
                acc[i][j] = __builtin_amdgcn_mfma_f32_16x16x32_bf16(a[i], b[j], acc[i][j], 0, 0, 0);
    }

    // C/D layout: col = lane&15, row = (lane>>4)*4 + reg
    #pragma unroll
    for (int i = 0; i < 4; ++i) {
        #pragma unroll
        for (int r = 0; r < 4; ++r) {
            int grow = row0 + wm * 64 + i * 16 + lk * 4 + r;
            if (grow >= M) continue;
            #pragma unroll
            for (int j = 0; j < 4; ++j) {
                int gcol = col0 + wn * 64 + j * 16 + lr;
                C[(size_t)grow * 256 + gcol] = acc[i][j][r] + bias[gcol];
            }
        }
    }
}

// ---------------- CSR build ----------------
__global__ void hist_kernel(const int* __restrict__ col, int* __restrict__ cnt) {
    int e = blockIdx.x * blockDim.x + threadIdx.x;
    if (e < N_EDGES) atomicAdd(&cnt[col[e]], 1);
}

__global__ __launch_bounds__(1024) void scan_kernel(int* __restrict__ cnt, int* __restrict__ offs) {
    __shared__ int sums[1024];
    const int t = threadIdx.x;
    const int chunk = (N_NODES + 1023) >> 10;
    const int base = t * chunk;
    int s = 0;
    for (int i = 0; i < chunk; ++i) {
        int idx = base + i;
        if (idx < N_NODES) s += cnt[idx];
    }
    sums[t] = s;
    __syncthreads();
    for (int d = 1; d < 1024; d <<= 1) {
        int v = (t >= d) ? sums[t - d] : 0;
        __syncthreads();
        sums[t] += v;
        __syncthreads();
    }
    int run = (t == 0) ? 0 : sums[t - 1];
    for (int i = 0; i < chunk; ++i) {
        int idx = base + i;
        if (idx < N_NODES) {
            int v = cnt[idx];
            offs[idx] = run;
            cnt[idx] = run;
            run += v;
        }
    }
    if (t == 1023) offs[N_NODES] = sums[1023];
}

__global__ void scatter_kernel(const int* __restrict__ row, const int* __restrict__ col,
                               int* __restrict__ cursor,
                               int* __restrict__ eidx, int* __restrict__ esrc) {
    int e = blockIdx.x * blockDim.x + threadIdx.x;
    if (e >= N_EDGES) return;
    int c = col[e];
    int p = atomicAdd(&cursor[c], 1);
    eidx[p] = e;
    esrc[p] = row[e];
}

// ---------------- edge scores: one thread per (edge, head) ----------------
__global__ void scores_kernel(const float* __restrict__ Q, const float* __restrict__ K,
                              const float* __restrict__ rel,
                              const int* __restrict__ row, const int* __restrict__ col,
                              float* __restrict__ scores) {
    int gid = blockIdx.x * blockDim.x + threadIdx.x;
    if (gid >= N_EDGES * NHEAD) return;
    int e = gid >> 3, h = gid & 7;
    int c = col[e], r = row[e];
    const float4* q4 = (const float4*)(Q + (size_t)c * DIM + h * DKH);
    const float4* k4 = (const float4*)(K + (size_t)r * DIM + h * DKH);
    const float4* r4 = (const float4*)(rel + h * DKH);
    float s = 0.f;
    #pragma unroll
    for (int i = 0; i < 8; ++i) {
        float4 q = q4[i], k = k4[i], rr = r4[i];
        s += q.x * (k.x + rr.x) + q.y * (k.y + rr.y)
           + q.z * (k.z + rr.z) + q.w * (k.w + rr.w);
    }
    scores[gid] = s * 0.17677669529663687f;  // 1/sqrt(32)
}

// ---------------- per-node segment softmax + V aggregation, bf16 output ----------------
__global__ __launch_bounds__(256) void node_kernel(
    const float* __restrict__ scores, const float* __restrict__ V,
    const int* __restrict__ offs, const int* __restrict__ eidx, const int* __restrict__ esrc,
    unsigned short* __restrict__ out_aggb)
{
    int wid = (blockIdx.x * blockDim.x + threadIdx.x) >> 6;
    int lane = threadIdx.x & 63;
    if (wid >= N_NODES) return;
    int beg = offs[wid], end = offs[wid + 1];
    int h = lane >> 3, sub = lane & 7;

    float m = -1e30f;
    for (int j = beg + sub; j < end; j += 8)
        m = fmaxf(m, scores[(size_t)eidx[j] * NHEAD + h]);
    m = fmaxf(m, __shfl_xor(m, 1));
    m = fmaxf(m, __shfl_xor(m, 2));
    m = fmaxf(m, __shfl_xor(m, 4));

    float den = 0.f;
    for (int j = beg + sub; j < end; j += 8)
        den += __expf(scores[(size_t)eidx[j] * NHEAD + h] - m);
    den += __shfl_xor(den, 1);
    den += __shfl_xor(den, 2);
    den += __shfl_xor(den, 4);
    float rden = (end > beg) ? 1.f / den : 0.f;

    float4 acc = make_float4(0.f, 0.f, 0.f, 0.f);
    int d0 = lane * 4;
    for (int j = beg; j < end; ++j) {
        int r = esrc[j];
        float w = __expf(scores[(size_t)eidx[j] * NHEAD + h] - m) * rden;
        float4 v = *(const float4*)(V + (size_t)r * DIM + d0);
        acc.x += w * v.x; acc.y += w * v.y; acc.z += w * v.z; acc.w += w * v.w;
    }
    u16x4 o = { f2bf(acc.x), f2bf(acc.y), f2bf(acc.z), f2bf(acc.w) };
    *(u16x4*)(out_aggb + (size_t)wid * DIM + d0) = o;
}

extern "C" void kernel_launch(void* const* d_in, const int* in_sizes, int n_in,
                              void* d_out, int out_size, void* d_ws, size_t ws_size,
                              hipStream_t stream) {
    const float* x    = (const float*)d_in[0];
    const int*   row  = (const int*)d_in[1];
    const int*   col  = (const int*)d_in[2];
    const float* rel  = (const float*)d_in[3];
    const float* user = (const float*)d_in[4];
    const float* item = (const float*)d_in[5];
    const float* Wq   = (const float*)d_in[6];
    const float* bq   = (const float*)d_in[7];
    const float* Wk   = (const float*)d_in[8];
    const float* bk   = (const float*)d_in[9];
    const float* Wv   = (const float*)d_in[10];
    const float* bv   = (const float*)d_in[11];
    const float* Wo   = (const float*)d_in[12];
    const float* bo   = (const float*)d_in[13];

    char* ws = (char*)d_ws;
    size_t off = 0;
    auto alloc = [&](size_t bytes) -> void* {
        void* p = ws + off;
        off = (off + bytes + 255) & ~(size_t)255;
        return p;
    };
    float* Q        = (float*)alloc((size_t)N_NODES * DIM * 4);
    float* K        = (float*)alloc((size_t)N_NODES * DIM * 4);
    float* V        = (float*)alloc((size_t)N_NODES * DIM * 4);
    float* scores   = (float*)alloc((size_t)N_EDGES * NHEAD * 4);
    int*   cnt      = (int*)alloc((size_t)N_NODES * 4);
    int*   offs     = (int*)alloc((size_t)(N_NODES + 1) * 4);
    int*   eidx     = (int*)alloc((size_t)N_EDGES * 4);
    int*   esrc     = (int*)alloc((size_t)N_EDGES * 4);
    unsigned short* xb       = (unsigned short*)alloc((size_t)N_NODES * DIM * 2);
    unsigned short* tb       = (unsigned short*)alloc((size_t)N_NODES * DIM * 2);
    unsigned short* Wb       = (unsigned short*)alloc((size_t)4 * 65536 * 2);
    unsigned short* out_aggb = (unsigned short*)alloc((size_t)N_NODES * DIM * 2);

    unsigned short* Wqb = Wb;
    unsigned short* Wkb = Wb + 65536;
    unsigned short* Wvb = Wb + 131072;
    unsigned short* Wob = Wb + 196608;

    hipMemsetAsync(cnt, 0, (size_t)N_NODES * 4, stream);

    const int total4 = N_NODES * DIM / 4;
    cast_inputs_kernel<<<(total4 + 255) / 256, 256, 0, stream>>>(x, user, item, xb, tb);
    cast_w_kernel<<<(65536 + 255) / 256, 256, 0, stream>>>(Wq, Wk, Wv, Wo, Wb);

    dim3 gg((N_NODES + 127) / 128, 2);
    gemm_mfma_kernel<<<gg, 256, 0, stream>>>(tb, Wqb, bq, Q, N_NODES);
    gemm_mfma_kernel<<<gg, 256, 0, stream>>>(tb, Wkb, bk, K, N_NODES);
    gemm_mfma_kernel<<<gg, 256, 0, stream>>>(xb, Wvb, bv, V, N_NODES);

    hist_kernel<<<(N_EDGES + 255) / 256, 256, 0, stream>>>(col, cnt);
    scan_kernel<<<1, 1024, 0, stream>>>(cnt, offs);
    scatter_kernel<<<(N_EDGES + 255) / 256, 256, 0, stream>>>(row, col, cnt, eidx, esrc);

    scores_kernel<<<(N_EDGES * NHEAD + 255) / 256, 256, 0, stream>>>(Q, K, rel, row, col, scores);
    node_kernel<<<(N_NODES * 64 + 255) / 256, 256, 0, stream>>>(scores, V, offs, eidx, esrc, out_aggb);

    gemm_mfma_kernel<<<gg, 256, 0, stream>>>(out_aggb, Wob, bo, (float*)d_out, N_NODES);
}

// Round 3
// 497.911 us; speedup vs baseline: 6.8721x; 1.6463x over previous
//
#include <hip/hip_runtime.h>
#include <hip/hip_bf16.h>

#define N_NODES   50000
#define N_USERS   20000
#define N_EDGES   800000
#define DIM       256
#define NHEAD     8
#define DKH       32

typedef __attribute__((ext_vector_type(8))) short bf16x8;
typedef __attribute__((ext_vector_type(4))) float f32x4;
typedef __attribute__((ext_vector_type(4))) unsigned short u16x4;
typedef __attribute__((ext_vector_type(8))) unsigned short u16x8;

__device__ inline unsigned short f2bf(float f) {
    union { __hip_bfloat16 b; unsigned short u; } cv;
    cv.b = __float2bfloat16(f);
    return cv.u;
}
__device__ inline float bf2f(unsigned short u) {
    return __uint_as_float(((unsigned int)u) << 16);
}

// ---------------- input casts: fp32 -> bf16 ----------------
__global__ void cast_inputs_kernel(const float* __restrict__ x,
                                   const float* __restrict__ user,
                                   const float* __restrict__ item,
                                   unsigned short* __restrict__ xb,
                                   unsigned short* __restrict__ tb)
{
    int gid = blockIdx.x * blockDim.x + threadIdx.x;
    const int total4 = N_NODES * DIM / 4;
    if (gid >= total4) return;
    size_t e = (size_t)gid * 4;
    float4 xv = *(const float4*)(x + e);
    u16x4 xo = { f2bf(xv.x), f2bf(xv.y), f2bf(xv.z), f2bf(xv.w) };
    *(u16x4*)(xb + e) = xo;
    const size_t usplit = (size_t)N_USERS * DIM;
    const float* tsrc = (e < usplit) ? (user + e) : (item + (e - usplit));
    float4 tv = *(const float4*)tsrc;
    u16x4 to = { f2bf(tv.x), f2bf(tv.y), f2bf(tv.z), f2bf(tv.w) };
    *(u16x4*)(tb + e) = to;
}

__global__ void cast_w_kernel(const float* __restrict__ Wq, const float* __restrict__ Wk,
                              const float* __restrict__ Wv, const float* __restrict__ Wo,
                              unsigned short* __restrict__ Wb)
{
    int gid = blockIdx.x * blockDim.x + threadIdx.x;
    if (gid >= 65536) return;
    const float* srcs[4] = { Wq, Wk, Wv, Wo };
    int m = gid >> 14;
    int off = (gid & 16383) * 4;
    float4 v = *(const float4*)(srcs[m] + off);
    u16x4 o = { f2bf(v.x), f2bf(v.y), f2bf(v.z), f2bf(v.w) };
    *(u16x4*)(Wb + (size_t)m * 65536 + off) = o;
}

// ---------------- MFMA GEMM: C[M,256] = A @ W^T + b, templated epilogue ----------------
// MODE 0: fp32 C[M,256]   MODE 1: bf16 C[M,256]
// MODE 2: bf16 KV-interleaved (K half)   MODE 3: bf16 KV-interleaved (V half)
template<int MODE>
__global__ __launch_bounds__(256) void gemm_mfma_kernel(
    const unsigned short* __restrict__ A,
    const unsigned short* __restrict__ W,
    const float* __restrict__ bias,
    void* __restrict__ Cv, int M)
{
    __shared__ unsigned short Asm[128 * 256];
    __shared__ unsigned short Wsm[128 * 256];
    const int tid = threadIdx.x;
    const int lane = tid & 63, wid = tid >> 6;
    const int row0 = blockIdx.x * 128;
    const int col0 = blockIdx.y * 128;

    #pragma unroll
    for (int it = 0; it < 16; ++it) {
        int o = it * 4096 + tid * 16;
        int r = o >> 9;
        int cb = (o & 511) ^ ((r & 7) << 4);
        int ga = row0 + r; if (ga >= M) ga = M - 1;
        const char* srcA = (const char*)A + ((size_t)ga << 9) + cb;
        __builtin_amdgcn_global_load_lds(
            (const __attribute__((address_space(1))) unsigned int*)srcA,
            (__attribute__((address_space(3))) unsigned int*)((char*)Asm + it * 4096 + wid * 1024),
            16, 0, 0);
        const char* srcW = (const char*)W + ((size_t)(col0 + r) << 9) + cb;
        __builtin_amdgcn_global_load_lds(
            (const __attribute__((address_space(1))) unsigned int*)srcW,
            (__attribute__((address_space(3))) unsigned int*)((char*)Wsm + it * 4096 + wid * 1024),
            16, 0, 0);
    }
    __syncthreads();

    const int wm = wid >> 1, wn = wid & 1;
    const int lr = lane & 15, lk = lane >> 4;
    f32x4 acc[4][4];
    #pragma unroll
    for (int i = 0; i < 4; ++i)
        #pragma unroll
        for (int j = 0; j < 4; ++j) acc[i][j] = (f32x4){0.f, 0.f, 0.f, 0.f};

    #pragma unroll
    for (int ks = 0; ks < 8; ++ks) {
        bf16x8 a[4], b[4];
        #pragma unroll
        for (int i = 0; i < 4; ++i) {
            int r = wm * 64 + i * 16 + lr;
            int cb = (ks * 64 + lk * 16) ^ ((r & 7) << 4);
            a[i] = *(const bf16x8*)((const char*)Asm + r * 512 + cb);
        }
        #pragma unroll
        for (int j = 0; j < 4; ++j) {
            int r = wn * 64 + j * 16 + lr;
            int cb = (ks * 64 + lk * 16) ^ ((r & 7) << 4);
            b[j] = *(const bf16x8*)((const char*)Wsm + r * 512 + cb);
        }
        #pragma unroll
        for (int i = 0; i < 4; ++i)
            #pragma unroll
            for (int j = 0; j < 4; ++j)
                acc[i][j] = __builtin_amdgcn_mfma_f32_16x16x32_bf16(a[i], b[j], acc[i][j], 0, 0, 0);
    }

    float* Cf = (float*)Cv;
    unsigned short* Cb = (unsigned short*)Cv;
    #pragma unroll
    for (int i = 0; i < 4; ++i) {
        #pragma unroll
        for (int r = 0; r < 4; ++r) {
            int grow = row0 + wm * 64 + i * 16 + lk * 4 + r;
            if (grow >= M) continue;
            #pragma unroll
            for (int j = 0; j < 4; ++j) {
                int gcol = col0 + wn * 64 + j * 16 + lr;
                float val = acc[i][j][r] + bias[gcol];
                if constexpr (MODE == 0) {
                    Cf[(size_t)grow * 256 + gcol] = val;
                } else if constexpr (MODE == 1) {
                    Cb[(size_t)grow * 256 + gcol] = f2bf(val);
                } else if constexpr (MODE == 2) {
                    Cb[(size_t)grow * 512 + ((gcol >> 2) << 3) + (gcol & 3)] = f2bf(val);
                } else {
                    Cb[(size_t)grow * 512 + ((gcol >> 2) << 3) + (gcol & 3) + 4] = f2bf(val);
                }
            }
        }
    }
}

// ---------------- CSR build ----------------
__global__ void hist_kernel(const int* __restrict__ col, int* __restrict__ cnt) {
    int e = blockIdx.x * blockDim.x + threadIdx.x;
    if (e < N_EDGES) atomicAdd(&cnt[col[e]], 1);
}

__global__ __launch_bounds__(1024) void scan_kernel(int* __restrict__ cnt, int* __restrict__ offs) {
    __shared__ int sums[1024];
    const int t = threadIdx.x;
    const int chunk = (N_NODES + 1023) >> 10;
    const int base = t * chunk;
    int s = 0;
    for (int i = 0; i < chunk; ++i) {
        int idx = base + i;
        if (idx < N_NODES) s += cnt[idx];
    }
    sums[t] = s;
    __syncthreads();
    for (int d = 1; d < 1024; d <<= 1) {
        int v = (t >= d) ? sums[t - d] : 0;
        __syncthreads();
        sums[t] += v;
        __syncthreads();
    }
    int run = (t == 0) ? 0 : sums[t - 1];
    for (int i = 0; i < chunk; ++i) {
        int idx = base + i;
        if (idx < N_NODES) {
            int v = cnt[idx];
            offs[idx] = run;
            cnt[idx] = run;
            run += v;
        }
    }
    if (t == 1023) offs[N_NODES] = sums[1023];
}

__global__ void scatter_kernel(const int* __restrict__ row, const int* __restrict__ col,
                               int* __restrict__ cursor, int* __restrict__ esrc) {
    int e = blockIdx.x * blockDim.x + threadIdx.x;
    if (e >= N_EDGES) return;
    int c = col[e];
    int p = atomicAdd(&cursor[c], 1);
    esrc[p] = row[e];
}

// ---------------- fused edge phase: one wave per destination node ----------------
// score = q.(k+rel)/sqrt(32); softmax WITHOUT max-shift (scores bounded, shift-invariant);
// single pass: den += e^s, acc += e^s * v. KV interleaved: 16B/lane per edge.
__global__ __launch_bounds__(256) void node_fused_kernel(
    const unsigned short* __restrict__ Qb, const unsigned short* __restrict__ KVb,
    const float* __restrict__ rel,
    const int* __restrict__ offs, const int* __restrict__ esrc,
    unsigned short* __restrict__ out_aggb)
{
    int wid = (blockIdx.x * blockDim.x + threadIdx.x) >> 6;
    int lane = threadIdx.x & 63;
    if (wid >= N_NODES) return;
    int beg = offs[wid], end = offs[wid + 1];
    int d0 = lane * 4;

    u16x4 qb = *(const u16x4*)(Qb + (size_t)wid * DIM + d0);
    float4 q = make_float4(bf2f(qb[0]), bf2f(qb[1]), bf2f(qb[2]), bf2f(qb[3]));
    float4 rl = *(const float4*)(rel + d0);

    // hoist q.rel (constant across edges), reduce within 8-lane head group
    float p0 = q.x * rl.x + q.y * rl.y + q.z * rl.z + q.w * rl.w;
    p0 += __shfl_xor(p0, 1);
    p0 += __shfl_xor(p0, 2);
    p0 += __shfl_xor(p0, 4);

    float den = 0.f;
    float4 acc = make_float4(0.f, 0.f, 0.f, 0.f);
    for (int j = beg; j < end; ++j) {
        int r = esrc[j];
        u16x8 kv = *(const u16x8*)(KVb + (size_t)r * 512 + lane * 8);
        float p = q.x * bf2f(kv[0]) + q.y * bf2f(kv[1])
                + q.z * bf2f(kv[2]) + q.w * bf2f(kv[3]);
        p += __shfl_xor(p, 1);
        p += __shfl_xor(p, 2);
        p += __shfl_xor(p, 4);
        float w = __expf((p + p0) * 0.17677669529663687f);
        den += w;
        acc.x += w * bf2f(kv[4]); acc.y += w * bf2f(kv[5]);
        acc.z += w * bf2f(kv[6]); acc.w += w * bf2f(kv[7]);
    }
    float rden = (end > beg) ? 1.f / den : 0.f;
    u16x4 o = { f2bf(acc.x * rden), f2bf(acc.y * rden),
                f2bf(acc.z * rden), f2bf(acc.w * rden) };
    *(u16x4*)(out_aggb + (size_t)wid * DIM + d0) = o;
}

extern "C" void kernel_launch(void* const* d_in, const int* in_sizes, int n_in,
                              void* d_out, int out_size, void* d_ws, size_t ws_size,
                              hipStream_t stream) {
    const float* x    = (const float*)d_in[0];
    const int*   row  = (const int*)d_in[1];
    const int*   col  = (const int*)d_in[2];
    const float* rel  = (const float*)d_in[3];
    const float* user = (const float*)d_in[4];
    const float* item = (const float*)d_in[5];
    const float* Wq   = (const float*)d_in[6];
    const float* bq   = (const float*)d_in[7];
    const float* Wk   = (const float*)d_in[8];
    const float* bk   = (const float*)d_in[9];
    const float* Wv   = (const float*)d_in[10];
    const float* bv   = (const float*)d_in[11];
    const float* Wo   = (const float*)d_in[12];
    const float* bo   = (const float*)d_in[13];

    char* ws = (char*)d_ws;
    size_t off = 0;
    auto alloc = [&](size_t bytes) -> void* {
        void* p = ws + off;
        off = (off + bytes + 255) & ~(size_t)255;
        return p;
    };
    unsigned short* Qb       = (unsigned short*)alloc((size_t)N_NODES * DIM * 2);
    unsigned short* KVb      = (unsigned short*)alloc((size_t)N_NODES * DIM * 2 * 2);
    unsigned short* out_aggb = (unsigned short*)alloc((size_t)N_NODES * DIM * 2);
    unsigned short* xb       = (unsigned short*)alloc((size_t)N_NODES * DIM * 2);
    unsigned short* tb       = (unsigned short*)alloc((size_t)N_NODES * DIM * 2);
    unsigned short* Wb       = (unsigned short*)alloc((size_t)4 * 65536 * 2);
    int*   cnt  = (int*)alloc((size_t)N_NODES * 4);
    int*   offs = (int*)alloc((size_t)(N_NODES + 1) * 4);
    int*   esrc = (int*)alloc((size_t)N_EDGES * 4);

    unsigned short* Wqb = Wb;
    unsigned short* Wkb = Wb + 65536;
    unsigned short* Wvb = Wb + 131072;
    unsigned short* Wob = Wb + 196608;

    hipMemsetAsync(cnt, 0, (size_t)N_NODES * 4, stream);

    const int total4 = N_NODES * DIM / 4;
    cast_inputs_kernel<<<(total4 + 255) / 256, 256, 0, stream>>>(x, user, item, xb, tb);
    cast_w_kernel<<<(65536 + 255) / 256, 256, 0, stream>>>(Wq, Wk, Wv, Wo, Wb);

    dim3 gg((N_NODES + 127) / 128, 2);
    gemm_mfma_kernel<1><<<gg, 256, 0, stream>>>(tb, Wqb, bq, Qb, N_NODES);
    gemm_mfma_kernel<2><<<gg, 256, 0, stream>>>(tb, Wkb, bk, KVb, N_NODES);
    gemm_mfma_kernel<3><<<gg, 256, 0, stream>>>(xb, Wvb, bv, KVb, N_NODES);

    hist_kernel<<<(N_EDGES + 255) / 256, 256, 0, stream>>>(col, cnt);
    scan_kernel<<<1, 1024, 0, stream>>>(cnt, offs);
    scatter_kernel<<<(N_EDGES + 255) / 256, 256, 0, stream>>>(row, col, cnt, esrc);

    node_fused_kernel<<<(N_NODES * 64 + 255) / 256, 256, 0, stream>>>(
        Qb, KVb, rel, offs, esrc, out_aggb);

    gemm_mfma_kernel<0><<<gg, 256, 0, stream>>>(out_aggb, Wob, bo, (float*)d_out, N_NODES);
}

// Round 4
// 386.261 us; speedup vs baseline: 8.8585x; 1.2891x over previous
//
#include <hip/hip_runtime.h>
#include <hip/hip_bf16.h>

#define N_NODES   50000
#define N_USERS   20000
#define N_EDGES   800000
#define DIM       256
#define NHEAD     8
#define DKH       32
#define NBLK_SCAN ((N_NODES + 255) / 256)   // 196

typedef __attribute__((ext_vector_type(8))) short bf16x8;
typedef __attribute__((ext_vector_type(4))) float f32x4;
typedef __attribute__((ext_vector_type(4))) unsigned short u16x4;
typedef __attribute__((ext_vector_type(8))) unsigned short u16x8;

__device__ inline unsigned short f2bf(float f) {
    union { __hip_bfloat16 b; unsigned short u; } cv;
    cv.b = __float2bfloat16(f);
    return cv.u;
}
__device__ inline float bf2f(unsigned short u) {
    return __uint_as_float(((unsigned int)u) << 16);
}

// ---------------- input casts: fp32 -> bf16 ----------------
__global__ void cast_inputs_kernel(const float* __restrict__ x,
                                   const float* __restrict__ user,
                                   const float* __restrict__ item,
                                   unsigned short* __restrict__ xb,
                                   unsigned short* __restrict__ tb)
{
    int gid = blockIdx.x * blockDim.x + threadIdx.x;
    const int total4 = N_NODES * DIM / 4;
    if (gid >= total4) return;
    size_t e = (size_t)gid * 4;
    float4 xv = *(const float4*)(x + e);
    u16x4 xo = { f2bf(xv.x), f2bf(xv.y), f2bf(xv.z), f2bf(xv.w) };
    *(u16x4*)(xb + e) = xo;
    const size_t usplit = (size_t)N_USERS * DIM;
    const float* tsrc = (e < usplit) ? (user + e) : (item + (e - usplit));
    float4 tv = *(const float4*)tsrc;
    u16x4 to = { f2bf(tv.x), f2bf(tv.y), f2bf(tv.z), f2bf(tv.w) };
    *(u16x4*)(tb + e) = to;
}

__global__ void cast_w_kernel(const float* __restrict__ Wq, const float* __restrict__ Wk,
                              const float* __restrict__ Wv, const float* __restrict__ Wo,
                              unsigned short* __restrict__ Wb)
{
    int gid = blockIdx.x * blockDim.x + threadIdx.x;
    if (gid >= 65536) return;
    const float* srcs[4] = { Wq, Wk, Wv, Wo };
    int m = gid >> 14;
    int off = (gid & 16383) * 4;
    float4 v = *(const float4*)(srcs[m] + off);
    u16x4 o = { f2bf(v.x), f2bf(v.y), f2bf(v.z), f2bf(v.w) };
    *(u16x4*)(Wb + (size_t)m * 65536 + off) = o;
}

// ---------------- MFMA GEMM: C[M,256] = A @ W^T + b, templated epilogue ----------------
// MODE 0: fp32 C   MODE 1: bf16 C   MODE 2: bf16 KV-interleave K-half   MODE 3: V-half
template<int MODE>
__global__ __launch_bounds__(256) void gemm_mfma_kernel(
    const unsigned short* __restrict__ A,
    const unsigned short* __restrict__ W,
    const float* __restrict__ bias,
    void* __restrict__ Cv, int M)
{
    __shared__ unsigned short Asm[128 * 256];
    __shared__ unsigned short Wsm[128 * 256];
    const int tid = threadIdx.x;
    const int lane = tid & 63, wid = tid >> 6;
    const int row0 = blockIdx.x * 128;
    const int col0 = blockIdx.y * 128;

    #pragma unroll
    for (int it = 0; it < 16; ++it) {
        int o = it * 4096 + tid * 16;
        int r = o >> 9;
        int cb = (o & 511) ^ ((r & 7) << 4);
        int ga = row0 + r; if (ga >= M) ga = M - 1;
        const char* srcA = (const char*)A + ((size_t)ga << 9) + cb;
        __builtin_amdgcn_global_load_lds(
            (const __attribute__((address_space(1))) unsigned int*)srcA,
            (__attribute__((address_space(3))) unsigned int*)((char*)Asm + it * 4096 + wid * 1024),
            16, 0, 0);
        const char* srcW = (const char*)W + ((size_t)(col0 + r) << 9) + cb;
        __builtin_amdgcn_global_load_lds(
            (const __attribute__((address_space(1))) unsigned int*)srcW,
            (__attribute__((address_space(3))) unsigned int*)((char*)Wsm + it * 4096 + wid * 1024),
            16, 0, 0);
    }
    __syncthreads();

    const int wm = wid >> 1, wn = wid & 1;
    const int lr = lane & 15, lk = lane >> 4;
    f32x4 acc[4][4];
    #pragma unroll
    for (int i = 0; i < 4; ++i)
        #pragma unroll
        for (int j = 0; j < 4; ++j) acc[i][j] = (f32x4){0.f, 0.f, 0.f, 0.f};

    #pragma unroll
    for (int ks = 0; ks < 8; ++ks) {
        bf16x8 a[4], b[4];
        #pragma unroll
        for (int i = 0; i < 4; ++i) {
            int r = wm * 64 + i * 16 + lr;
            int cb = (ks * 64 + lk * 16) ^ ((r & 7) << 4);
            a[i] = *(const bf16x8*)((const char*)Asm + r * 512 + cb);
        }
        #pragma unroll
        for (int j = 0; j < 4; ++j) {
            int r = wn * 64 + j * 16 + lr;
            int cb = (ks * 64 + lk * 16) ^ ((r & 7) << 4);
            b[j] = *(const bf16x8*)((const char*)Wsm + r * 512 + cb);
        }
        #pragma unroll
        for (int i = 0; i < 4; ++i)
            #pragma unroll
            for (int j = 0; j < 4; ++j)
                acc[i][j] = __builtin_amdgcn_mfma_f32_16x16x32_bf16(a[i], b[j], acc[i][j], 0, 0, 0);
    }

    float* Cf = (float*)Cv;
    unsigned short* Cb = (unsigned short*)Cv;
    #pragma unroll
    for (int i = 0; i < 4; ++i) {
        #pragma unroll
        for (int r = 0; r < 4; ++r) {
            int grow = row0 + wm * 64 + i * 16 + lk * 4 + r;
            if (grow >= M) continue;
            #pragma unroll
            for (int j = 0; j < 4; ++j) {
                int gcol = col0 + wn * 64 + j * 16 + lr;
                float val = acc[i][j][r] + bias[gcol];
                if constexpr (MODE == 0) {
                    Cf[(size_t)grow * 256 + gcol] = val;
                } else if constexpr (MODE == 1) {
                    Cb[(size_t)grow * 256 + gcol] = f2bf(val);
                } else if constexpr (MODE == 2) {
                    Cb[(size_t)grow * 512 + ((gcol >> 2) << 3) + (gcol & 3)] = f2bf(val);
                } else {
                    Cb[(size_t)grow * 512 + ((gcol >> 2) << 3) + (gcol & 3) + 4] = f2bf(val);
                }
            }
        }
    }
}

// ---------------- CSR build ----------------
__global__ void hist_kernel(const int* __restrict__ col, int* __restrict__ cnt) {
    int e = blockIdx.x * blockDim.x + threadIdx.x;
    if (e < N_EDGES) atomicAdd(&cnt[col[e]], 1);
}

// 3-phase multi-block exclusive scan (replaces 126us single-block scan)
__global__ __launch_bounds__(256) void scan_blk_kernel(const int* __restrict__ cnt,
                                                       int* __restrict__ offs_tmp,
                                                       int* __restrict__ bsum) {
    __shared__ int s[256];
    int b = blockIdx.x, t = threadIdx.x;
    int i = b * 256 + t;
    int v = (i < N_NODES) ? cnt[i] : 0;
    s[t] = v;
    __syncthreads();
    #pragma unroll
    for (int d = 1; d < 256; d <<= 1) {
        int u = (t >= d) ? s[t - d] : 0;
        __syncthreads();
        s[t] += u;
        __syncthreads();
    }
    if (i < N_NODES) offs_tmp[i] = s[t] - v;   // exclusive within block
    if (t == 255) bsum[b] = s[255];
}

__global__ __launch_bounds__(256) void scan_top_kernel(int* __restrict__ bsum) {
    __shared__ int s[256];
    int t = threadIdx.x;
    int v = (t < NBLK_SCAN) ? bsum[t] : 0;
    s[t] = v;
    __syncthreads();
    #pragma unroll
    for (int d = 1; d < 256; d <<= 1) {
        int u = (t >= d) ? s[t - d] : 0;
        __syncthreads();
        s[t] += u;
        __syncthreads();
    }
    if (t < NBLK_SCAN) bsum[t] = s[t] - v;     // exclusive block offsets
}

__global__ __launch_bounds__(256) void scan_add_kernel(const int* __restrict__ offs_tmp,
                                                       const int* __restrict__ bsum,
                                                       int* __restrict__ offs,
                                                       int* __restrict__ cursor) {
    int i = blockIdx.x * 256 + threadIdx.x;
    if (i == 0) offs[N_NODES] = N_EDGES;
    if (i >= N_NODES) return;
    int o = offs_tmp[i] + bsum[blockIdx.x];
    offs[i] = o;
    cursor[i] = o;
}

__global__ void scatter_kernel(const int* __restrict__ row, const int* __restrict__ col,
                               int* __restrict__ cursor, int* __restrict__ esrc) {
    int e = blockIdx.x * blockDim.x + threadIdx.x;
    if (e >= N_EDGES) return;
    int c = col[e];
    int p = atomicAdd(&cursor[c], 1);
    esrc[p] = row[e];
}

// ---------------- fused edge phase: one wave per destination node ----------------
__global__ __launch_bounds__(256) void node_fused_kernel(
    const unsigned short* __restrict__ Qb, const unsigned short* __restrict__ KVb,
    const float* __restrict__ rel,
    const int* __restrict__ offs, const int* __restrict__ esrc,
    unsigned short* __restrict__ out_aggb)
{
    int wid = (blockIdx.x * blockDim.x + threadIdx.x) >> 6;
    int lane = threadIdx.x & 63;
    if (wid >= N_NODES) return;
    int beg = offs[wid], end = offs[wid + 1];
    int d0 = lane * 4;

    u16x4 qb = *(const u16x4*)(Qb + (size_t)wid * DIM + d0);
    float4 q = make_float4(bf2f(qb[0]), bf2f(qb[1]), bf2f(qb[2]), bf2f(qb[3]));
    float4 rl = *(const float4*)(rel + d0);

    float p0 = q.x * rl.x + q.y * rl.y + q.z * rl.z + q.w * rl.w;
    p0 += __shfl_xor(p0, 1);
    p0 += __shfl_xor(p0, 2);
    p0 += __shfl_xor(p0, 4);

    float den = 0.f;
    float4 acc = make_float4(0.f, 0.f, 0.f, 0.f);
    for (int j = beg; j < end; ++j) {
        int r = esrc[j];
        u16x8 kv = *(const u16x8*)(KVb + (size_t)r * 512 + lane * 8);
        float p = q.x * bf2f(kv[0]) + q.y * bf2f(kv[1])
                + q.z * bf2f(kv[2]) + q.w * bf2f(kv[3]);
        p += __shfl_xor(p, 1);
        p += __shfl_xor(p, 2);
        p += __shfl_xor(p, 4);
        float w = __expf((p + p0) * 0.17677669529663687f);
        den += w;
        acc.x += w * bf2f(kv[4]); acc.y += w * bf2f(kv[5]);
        acc.z += w * bf2f(kv[6]); acc.w += w * bf2f(kv[7]);
    }
    float rden = (end > beg) ? 1.f / den : 0.f;
    u16x4 o = { f2bf(acc.x * rden), f2bf(acc.y * rden),
                f2bf(acc.z * rden), f2bf(acc.w * rden) };
    *(u16x4*)(out_aggb + (size_t)wid * DIM + d0) = o;
}

extern "C" void kernel_launch(void* const* d_in, const int* in_sizes, int n_in,
                              void* d_out, int out_size, void* d_ws, size_t ws_size,
                              hipStream_t stream) {
    const float* x    = (const float*)d_in[0];
    const int*   row  = (const int*)d_in[1];
    const int*   col  = (const int*)d_in[2];
    const float* rel  = (const float*)d_in[3];
    const float* user = (const float*)d_in[4];
    const float* item = (const float*)d_in[5];
    const float* Wq   = (const float*)d_in[6];
    const float* bq   = (const float*)d_in[7];
    const float* Wk   = (const float*)d_in[8];
    const float* bk   = (const float*)d_in[9];
    const float* Wv   = (const float*)d_in[10];
    const float* bv   = (const float*)d_in[11];
    const float* Wo   = (const float*)d_in[12];
    const float* bo   = (const float*)d_in[13];

    char* ws = (char*)d_ws;
    size_t off = 0;
    auto alloc = [&](size_t bytes) -> void* {
        void* p = ws + off;
        off = (off + bytes + 255) & ~(size_t)255;
        return p;
    };
    unsigned short* Qb       = (unsigned short*)alloc((size_t)N_NODES * DIM * 2);
    unsigned short* KVb      = (unsigned short*)alloc((size_t)N_NODES * DIM * 2 * 2);
    unsigned short* out_aggb = (unsigned short*)alloc((size_t)N_NODES * DIM * 2);
    unsigned short* xb       = (unsigned short*)alloc((size_t)N_NODES * DIM * 2);
    unsigned short* tb       = (unsigned short*)alloc((size_t)N_NODES * DIM * 2);
    unsigned short* Wb       = (unsigned short*)alloc((size_t)4 * 65536 * 2);
    int*   cnt      = (int*)alloc((size_t)N_NODES * 4);
    int*   offs     = (int*)alloc((size_t)(N_NODES + 1) * 4);
    int*   offs_tmp = (int*)alloc((size_t)N_NODES * 4);
    int*   bsum     = (int*)alloc((size_t)NBLK_SCAN * 4);
    int*   esrc     = (int*)alloc((size_t)N_EDGES * 4);

    unsigned short* Wqb = Wb;
    unsigned short* Wkb = Wb + 65536;
    unsigned short* Wvb = Wb + 131072;
    unsigned short* Wob = Wb + 196608;

    hipMemsetAsync(cnt, 0, (size_t)N_NODES * 4, stream);

    const int total4 = N_NODES * DIM / 4;
    cast_inputs_kernel<<<(total4 + 255) / 256, 256, 0, stream>>>(x, user, item, xb, tb);
    cast_w_kernel<<<(65536 + 255) / 256, 256, 0, stream>>>(Wq, Wk, Wv, Wo, Wb);

    dim3 gg((N_NODES + 127) / 128, 2);
    gemm_mfma_kernel<1><<<gg, 256, 0, stream>>>(tb, Wqb, bq, Qb, N_NODES);
    gemm_mfma_kernel<2><<<gg, 256, 0, stream>>>(tb, Wkb, bk, KVb, N_NODES);
    gemm_mfma_kernel<3><<<gg, 256, 0, stream>>>(xb, Wvb, bv, KVb, N_NODES);

    hist_kernel<<<(N_EDGES + 255) / 256, 256, 0, stream>>>(col, cnt);
    scan_blk_kernel<<<NBLK_SCAN, 256, 0, stream>>>(cnt, offs_tmp, bsum);
    scan_top_kernel<<<1, 256, 0, stream>>>(bsum);
    scan_add_kernel<<<NBLK_SCAN, 256, 0, stream>>>(offs_tmp, bsum, offs, cnt);
    scatter_kernel<<<(N_EDGES + 255) / 256, 256, 0, stream>>>(row, col, cnt, esrc);

    node_fused_kernel<<<(N_NODES * 64 + 255) / 256, 256, 0, stream>>>(
        Qb, KVb, rel, offs, esrc, out_aggb);

    gemm_mfma_kernel<0><<<gg, 256, 0, stream>>>(out_aggb, Wob, bo, (float*)d_out, N_NODES);
}

// Round 5
// 360.309 us; speedup vs baseline: 9.4965x; 1.0720x over previous
//
#include <hip/hip_runtime.h>
#include <hip/hip_bf16.h>

#define N_NODES   50000
#define N_USERS   20000
#define N_EDGES   800000
#define DIM       256
#define NHEAD     8
#define DKH       32
#define NBLK_SCAN ((N_NODES + 255) / 256)   // 196

typedef __attribute__((ext_vector_type(8))) short bf16x8;
typedef __attribute__((ext_vector_type(4))) float f32x4;
typedef __attribute__((ext_vector_type(4))) unsigned short u16x4;
typedef __attribute__((ext_vector_type(8))) unsigned short u16x8;

__device__ inline unsigned short f2bf(float f) {
    union { __hip_bfloat16 b; unsigned short u; } cv;
    cv.b = __float2bfloat16(f);
    return cv.u;
}
__device__ inline float bf2f(unsigned short u) {
    return __uint_as_float(((unsigned int)u) << 16);
}

// ---------------- weight cast: fp32 -> bf16 (1 MB total, trivial) ----------------
__global__ void cast_w_kernel(const float* __restrict__ Wq, const float* __restrict__ Wk,
                              const float* __restrict__ Wv, const float* __restrict__ Wo,
                              unsigned short* __restrict__ Wb)
{
    int gid = blockIdx.x * blockDim.x + threadIdx.x;
    if (gid >= 65536) return;
    const float* srcs[4] = { Wq, Wk, Wv, Wo };
    int m = gid >> 14;
    int off = (gid & 16383) * 4;
    float4 v = *(const float4*)(srcs[m] + off);
    u16x4 o = { f2bf(v.x), f2bf(v.y), f2bf(v.z), f2bf(v.w) };
    *(u16x4*)(Wb + (size_t)m * 65536 + off) = o;
}

// ---------------- GEMM building blocks ----------------
// LDS layout: row-major [128][512B] with byte swizzle cb = c ^ ((row&7)<<4).

// A staged from fp32 (row split Alo/Ahi), converted in-register, swizzled ds_write.
__device__ __forceinline__ void stage_a_f32(const float* __restrict__ Alo,
                                            const float* __restrict__ Ahi,
                                            int split, int row0, int M,
                                            unsigned short* Asm, int tid)
{
    #pragma unroll
    for (int it = 0; it < 16; ++it) {
        int o = it * 4096 + tid * 16;
        int r = o >> 9;
        int ce = (o & 511) >> 1;               // bf16 elem index in row
        int ga = row0 + r; if (ga >= M) ga = M - 1;
        const float* src = ((ga < split) ? Alo + (size_t)ga * DIM
                                         : Ahi + (size_t)(ga - split) * DIM) + ce;
        float4 f0 = *(const float4*)src;
        float4 f1 = *(const float4*)(src + 4);
        u16x8 hv = { f2bf(f0.x), f2bf(f0.y), f2bf(f0.z), f2bf(f0.w),
                     f2bf(f1.x), f2bf(f1.y), f2bf(f1.z), f2bf(f1.w) };
        int cb = (o & 511) ^ ((r & 7) << 4);
        *(u16x8*)((char*)Asm + r * 512 + cb) = hv;
    }
}

// bf16 source staged via global_load_lds (linear dest, pre-swizzled source).
__device__ __forceinline__ void stage_bf16_lds(const unsigned short* __restrict__ S,
                                               int row0, int M, int clampM,
                                               unsigned short* Lsm, int tid, int wid)
{
    #pragma unroll
    for (int it = 0; it < 16; ++it) {
        int o = it * 4096 + tid * 16;
        int r = o >> 9;
        int cb = (o & 511) ^ ((r & 7) << 4);
        int ga = row0 + r;
        if (clampM && ga >= M) ga = M - 1;
        const char* src = (const char*)S + ((size_t)ga << 9) + cb;
        __builtin_amdgcn_global_load_lds(
            (const __attribute__((address_space(1))) unsigned int*)src,
            (__attribute__((address_space(3))) unsigned int*)((char*)Lsm + it * 4096 + wid * 1024),
            16, 0, 0);
    }
}

__device__ __forceinline__ void mfma_core(const unsigned short* Asm, const unsigned short* Wsm,
                                          f32x4 acc[4][4], int lane, int wid)
{
    const int wm = wid >> 1, wn = wid & 1;
    const int lr = lane & 15, lk = lane >> 4;
    #pragma unroll
    for (int ks = 0; ks < 8; ++ks) {
        bf16x8 a[4], b[4];
        #pragma unroll
        for (int i = 0; i < 4; ++i) {
            int r = wm * 64 + i * 16 + lr;
            int cb = (ks * 64 + lk * 16) ^ ((r & 7) << 4);
            a[i] = *(const bf16x8*)((const char*)Asm + r * 512 + cb);
        }
        #pragma unroll
        for (int j = 0; j < 4; ++j) {
            int r = wn * 64 + j * 16 + lr;
            int cb = (ks * 64 + lk * 16) ^ ((r & 7) << 4);
            b[j] = *(const bf16x8*)((const char*)Wsm + r * 512 + cb);
        }
        #pragma unroll
        for (int i = 0; i < 4; ++i)
            #pragma unroll
            for (int j = 0; j < 4; ++j)
                acc[i][j] = __builtin_amdgcn_mfma_f32_16x16x32_bf16(a[i], b[j], acc[i][j], 0, 0, 0);
    }
}

// Epilogue MODE: 0 = fp32 linear, 1 = bf16 linear, 2 = KV K-half, 3 = KV V-half
template<int MODE>
__device__ __forceinline__ void epilogue(f32x4 acc[4][4], const float* bias, void* Cv,
                                         int row0, int col0, int M, int lane, int wid)
{
    const int wm = wid >> 1, wn = wid & 1;
    const int lr = lane & 15, lk = lane >> 4;
    float* Cf = (float*)Cv;
    unsigned short* Cb = (unsigned short*)Cv;
    #pragma unroll
    for (int i = 0; i < 4; ++i) {
        #pragma unroll
        for (int r = 0; r < 4; ++r) {
            int grow = row0 + wm * 64 + i * 16 + lk * 4 + r;
            if (grow >= M) continue;
            #pragma unroll
            for (int j = 0; j < 4; ++j) {
                int gcol = col0 + wn * 64 + j * 16 + lr;
                float val = acc[i][j][r] + bias[gcol];
                if constexpr (MODE == 0) {
                    Cf[(size_t)grow * 256 + gcol] = val;
                } else if constexpr (MODE == 1) {
                    Cb[(size_t)grow * 256 + gcol] = f2bf(val);
                } else if constexpr (MODE == 2) {
                    Cb[(size_t)grow * 512 + ((gcol >> 2) << 3) + (gcol & 3)] = f2bf(val);
                } else {
                    Cb[(size_t)grow * 512 + ((gcol >> 2) << 3) + (gcol & 3) + 4] = f2bf(val);
                }
            }
        }
    }
}

// Fused Q+K GEMM from fp32 text source: grid.y in [0,4): sel = y>>1 (0:Q, 1:K), colblk = y&1
__global__ __launch_bounds__(256) void gemm_qk_kernel(
    const float* __restrict__ user, const float* __restrict__ item,
    const unsigned short* __restrict__ Wqb, const unsigned short* __restrict__ Wkb,
    const float* __restrict__ bq, const float* __restrict__ bk,
    unsigned short* __restrict__ Qb, unsigned short* __restrict__ KVb, int M)
{
    __shared__ unsigned short Asm[128 * 256];
    __shared__ unsigned short Wsm[128 * 256];
    const int tid = threadIdx.x;
    const int lane = tid & 63, wid = tid >> 6;
    const int row0 = blockIdx.x * 128;
    const int sel  = blockIdx.y >> 1;
    const int col0 = (blockIdx.y & 1) * 128;

    stage_bf16_lds(sel ? Wkb : Wqb, col0, 256, 0, Wsm, tid, wid);
    stage_a_f32(user, item, N_USERS, row0, M, Asm, tid);
    __syncthreads();

    f32x4 acc[4][4];
    #pragma unroll
    for (int i = 0; i < 4; ++i)
        #pragma unroll
        for (int j = 0; j < 4; ++j) acc[i][j] = (f32x4){0.f, 0.f, 0.f, 0.f};
    mfma_core(Asm, Wsm, acc, lane, wid);

    if (sel == 0) epilogue<1>(acc, bq, Qb, row0, col0, M, lane, wid);
    else          epilogue<2>(acc, bk, KVb, row0, col0, M, lane, wid);
}

// Generic GEMM: F32A=1 -> fp32 A (Alo/Ahi/split), F32A=0 -> bf16 A via global_load_lds
template<int MODE, int F32A>
__global__ __launch_bounds__(256) void gemm_mfma_kernel(
    const void* __restrict__ Alo, const void* __restrict__ Ahi, int split,
    const unsigned short* __restrict__ W, const float* __restrict__ bias,
    void* __restrict__ Cv, int M)
{
    __shared__ unsigned short Asm[128 * 256];
    __shared__ unsigned short Wsm[128 * 256];
    const int tid = threadIdx.x;
    const int lane = tid & 63, wid = tid >> 6;
    const int row0 = blockIdx.x * 128;
    const int col0 = blockIdx.y * 128;

    stage_bf16_lds(W, col0, 256, 0, Wsm, tid, wid);
    if constexpr (F32A) {
        stage_a_f32((const float*)Alo, (const float*)Ahi, split, row0, M, Asm, tid);
    } else {
        stage_bf16_lds((const unsigned short*)Alo, row0, M, 1, Asm, tid, wid);
    }
    __syncthreads();

    f32x4 acc[4][4];
    #pragma unroll
    for (int i = 0; i < 4; ++i)
        #pragma unroll
        for (int j = 0; j < 4; ++j) acc[i][j] = (f32x4){0.f, 0.f, 0.f, 0.f};
    mfma_core(Asm, Wsm, acc, lane, wid);
    epilogue<MODE>(acc, bias, Cv, row0, col0, M, lane, wid);
}

// ---------------- CSR build ----------------
__global__ void hist_kernel(const int* __restrict__ col, int* __restrict__ cnt) {
    int e = blockIdx.x * blockDim.x + threadIdx.x;
    if (e < N_EDGES) atomicAdd(&cnt[col[e]], 1);
}

__global__ __launch_bounds__(256) void scan_blk_kernel(const int* __restrict__ cnt,
                                                       int* __restrict__ offs_tmp,
                                                       int* __restrict__ bsum) {
    __shared__ int s[256];
    int b = blockIdx.x, t = threadIdx.x;
    int i = b * 256 + t;
    int v = (i < N_NODES) ? cnt[i] : 0;
    s[t] = v;
    __syncthreads();
    #pragma unroll
    for (int d = 1; d < 256; d <<= 1) {
        int u = (t >= d) ? s[t - d] : 0;
        __syncthreads();
        s[t] += u;
        __syncthreads();
    }
    if (i < N_NODES) offs_tmp[i] = s[t] - v;
    if (t == 255) bsum[b] = s[255];
}

__global__ __launch_bounds__(256) void scan_top_kernel(int* __restrict__ bsum) {
    __shared__ int s[256];
    int t = threadIdx.x;
    int v = (t < NBLK_SCAN) ? bsum[t] : 0;
    s[t] = v;
    __syncthreads();
    #pragma unroll
    for (int d = 1; d < 256; d <<= 1) {
        int u = (t >= d) ? s[t - d] : 0;
        __syncthreads();
        s[t] += u;
        __syncthreads();
    }
    if (t < NBLK_SCAN) bsum[t] = s[t] - v;
}

__global__ __launch_bounds__(256) void scan_add_kernel(const int* __restrict__ offs_tmp,
                                                       const int* __restrict__ bsum,
                                                       int* __restrict__ offs,
                                                       int* __restrict__ cursor) {
    int i = blockIdx.x * 256 + threadIdx.x;
    if (i == 0) offs[N_NODES] = N_EDGES;
    if (i >= N_NODES) return;
    int o = offs_tmp[i] + bsum[blockIdx.x];
    offs[i] = o;
    cursor[i] = o;
}

__global__ void scatter_kernel(const int* __restrict__ row, const int* __restrict__ col,
                               int* __restrict__ cursor, int* __restrict__ esrc) {
    int e = blockIdx.x * blockDim.x + threadIdx.x;
    if (e >= N_EDGES) return;
    int c = col[e];
    int p = atomicAdd(&cursor[c], 1);
    esrc[p] = row[e];
}

// ---------------- fused edge phase: one wave per destination node ----------------
// v2: lane-preloaded esrc (coalesced) + 4-way unroll -> 4 independent 1KB gathers in flight
__global__ __launch_bounds__(256) void node_fused_kernel(
    const unsigned short* __restrict__ Qb, const unsigned short* __restrict__ KVb,
    const float* __restrict__ rel,
    const int* __restrict__ offs, const int* __restrict__ esrc,
    unsigned short* __restrict__ out_aggb)
{
    const float SC = 0.17677669529663687f;  // 1/sqrt(32)
    int wid = (blockIdx.x * blockDim.x + threadIdx.x) >> 6;
    int lane = threadIdx.x & 63;
    if (wid >= N_NODES) return;
    int beg = offs[wid], end = offs[wid + 1];
    int d0 = lane * 4;

    u16x4 qb4 = *(const u16x4*)(Qb + (size_t)wid * DIM + d0);
    float qx = bf2f(qb4[0]), qy = bf2f(qb4[1]), qz = bf2f(qb4[2]), qw = bf2f(qb4[3]);
    float4 rl = *(const float4*)(rel + d0);

    float p0 = qx * rl.x + qy * rl.y + qz * rl.z + qw * rl.w;
    p0 += __shfl_xor(p0, 1);
    p0 += __shfl_xor(p0, 2);
    p0 += __shfl_xor(p0, 4);

    float den = 0.f;
    float4 acc = make_float4(0.f, 0.f, 0.f, 0.f);

    for (int base = beg; base < end; base += 64) {
        int n = end - base; if (n > 64) n = 64;
        int idx = base + lane; if (idx >= end) idx = end - 1;
        int my = esrc[idx];
        int j = 0;
        for (; j + 4 <= n; j += 4) {
            int r0 = __shfl(my, j),     r1 = __shfl(my, j + 1);
            int r2 = __shfl(my, j + 2), r3 = __shfl(my, j + 3);
            u16x8 k0 = *(const u16x8*)(KVb + (size_t)r0 * 512 + lane * 8);
            u16x8 k1 = *(const u16x8*)(KVb + (size_t)r1 * 512 + lane * 8);
            u16x8 k2 = *(const u16x8*)(KVb + (size_t)r2 * 512 + lane * 8);
            u16x8 k3 = *(const u16x8*)(KVb + (size_t)r3 * 512 + lane * 8);
            float s0 = qx * bf2f(k0[0]) + qy * bf2f(k0[1]) + qz * bf2f(k0[2]) + qw * bf2f(k0[3]);
            float s1 = qx * bf2f(k1[0]) + qy * bf2f(k1[1]) + qz * bf2f(k1[2]) + qw * bf2f(k1[3]);
            float s2 = qx * bf2f(k2[0]) + qy * bf2f(k2[1]) + qz * bf2f(k2[2]) + qw * bf2f(k2[3]);
            float s3 = qx * bf2f(k3[0]) + qy * bf2f(k3[1]) + qz * bf2f(k3[2]) + qw * bf2f(k3[3]);
            s0 += __shfl_xor(s0, 1); s1 += __shfl_xor(s1, 1); s2 += __shfl_xor(s2, 1); s3 += __shfl_xor(s3, 1);
            s0 += __shfl_xor(s0, 2); s1 += __shfl_xor(s1, 2); s2 += __shfl_xor(s2, 2); s3 += __shfl_xor(s3, 2);
            s0 += __shfl_xor(s0, 4); s1 += __shfl_xor(s1, 4); s2 += __shfl_xor(s2, 4); s3 += __shfl_xor(s3, 4);
            float w0 = __expf((s0 + p0) * SC);
            float w1 = __expf((s1 + p0) * SC);
            float w2 = __expf((s2 + p0) * SC);
            float w3 = __expf((s3 + p0) * SC);
            den += (w0 + w1) + (w2 + w3);
            acc.x += w0 * bf2f(k0[4]) + w1 * bf2f(k1[4]) + w2 * bf2f(k2[4]) + w3 * bf2f(k3[4]);
            acc.y += w0 * bf2f(k0[5]) + w1 * bf2f(k1[5]) + w2 * bf2f(k2[5]) + w3 * bf2f(k3[5]);
            acc.z += w0 * bf2f(k0[6]) + w1 * bf2f(k1[6]) + w2 * bf2f(k2[6]) + w3 * bf2f(k3[6]);
            acc.w += w0 * bf2f(k0[7]) + w1 * bf2f(k1[7]) + w2 * bf2f(k2[7]) + w3 * bf2f(k3[7]);
        }
        for (; j < n; ++j) {
            int r0 = __shfl(my, j);
            u16x8 k0 = *(const u16x8*)(KVb + (size_t)r0 * 512 + lane * 8);
            float s0 = qx * bf2f(k0[0]) + qy * bf2f(k0[1]) + qz * bf2f(k0[2]) + qw * bf2f(k0[3]);
            s0 += __shfl_xor(s0, 1);
            s0 += __shfl_xor(s0, 2);
            s0 += __shfl_xor(s0, 4);
            float w0 = __expf((s0 + p0) * SC);
            den += w0;
            acc.x += w0 * bf2f(k0[4]); acc.y += w0 * bf2f(k0[5]);
            acc.z += w0 * bf2f(k0[6]); acc.w += w0 * bf2f(k0[7]);
        }
    }
    float rden = (end > beg) ? 1.f / den : 0.f;
    u16x4 o = { f2bf(acc.x * rden), f2bf(acc.y * rden),
                f2bf(acc.z * rden), f2bf(acc.w * rden) };
    *(u16x4*)(out_aggb + (size_t)wid * DIM + d0) = o;
}

extern "C" void kernel_launch(void* const* d_in, const int* in_sizes, int n_in,
                              void* d_out, int out_size, void* d_ws, size_t ws_size,
                              hipStream_t stream) {
    const float* x    = (const float*)d_in[0];
    const int*   row  = (const int*)d_in[1];
    const int*   col  = (const int*)d_in[2];
    const float* rel  = (const float*)d_in[3];
    const float* user = (const float*)d_in[4];
    const float* item = (const float*)d_in[5];
    const float* Wq   = (const float*)d_in[6];
    const float* bq   = (const float*)d_in[7];
    const float* Wk   = (const float*)d_in[8];
    const float* bk   = (const float*)d_in[9];
    const float* Wv   = (const float*)d_in[10];
    const float* bv   = (const float*)d_in[11];
    const float* Wo   = (const float*)d_in[12];
    const float* bo   = (const float*)d_in[13];

    char* ws = (char*)d_ws;
    size_t off = 0;
    auto alloc = [&](size_t bytes) -> void* {
        void* p = ws + off;
        off = (off + bytes + 255) & ~(size_t)255;
        return p;
    };
    unsigned short* Qb       = (unsigned short*)alloc((size_t)N_NODES * DIM * 2);
    unsigned short* KVb      = (unsigned short*)alloc((size_t)N_NODES * DIM * 2 * 2);
    unsigned short* out_aggb = (unsigned short*)alloc((size_t)N_NODES * DIM * 2);
    unsigned short* Wb       = (unsigned short*)alloc((size_t)4 * 65536 * 2);
    int*   cnt      = (int*)alloc((size_t)N_NODES * 4);
    int*   offs     = (int*)alloc((size_t)(N_NODES + 1) * 4);
    int*   offs_tmp = (int*)alloc((size_t)N_NODES * 4);
    int*   bsum     = (int*)alloc((size_t)NBLK_SCAN * 4);
    int*   esrc     = (int*)alloc((size_t)N_EDGES * 4);

    unsigned short* Wqb = Wb;
    unsigned short* Wkb = Wb + 65536;
    unsigned short* Wvb = Wb + 131072;
    unsigned short* Wob = Wb + 196608;

    hipMemsetAsync(cnt, 0, (size_t)N_NODES * 4, stream);

    cast_w_kernel<<<(65536 + 255) / 256, 256, 0, stream>>>(Wq, Wk, Wv, Wo, Wb);
    hist_kernel<<<(N_EDGES + 255) / 256, 256, 0, stream>>>(col, cnt);
    scan_blk_kernel<<<NBLK_SCAN, 256, 0, stream>>>(cnt, offs_tmp, bsum);
    scan_top_kernel<<<1, 256, 0, stream>>>(bsum);
    scan_add_kernel<<<NBLK_SCAN, 256, 0, stream>>>(offs_tmp, bsum, offs, cnt);
    scatter_kernel<<<(N_EDGES + 255) / 256, 256, 0, stream>>>(row, col, cnt, esrc);

    const int gx = (N_NODES + 127) / 128;
    gemm_qk_kernel<<<dim3(gx, 4), 256, 0, stream>>>(user, item, Wqb, Wkb, bq, bk, Qb, KVb, N_NODES);
    gemm_mfma_kernel<3, 1><<<dim3(gx, 2), 256, 0, stream>>>(x, x, N_NODES, Wvb, bv, KVb, N_NODES);

    node_fused_kernel<<<(N_NODES * 64 + 255) / 256, 256, 0, stream>>>(
        Qb, KVb, rel, offs, esrc, out_aggb);

    gemm_mfma_kernel<0, 0><<<dim3(gx, 2), 256, 0, stream>>>(out_aggb, nullptr, 0, Wob, bo,
                                                            (float*)d_out, N_NODES);
}

// Round 6
// 352.804 us; speedup vs baseline: 9.6985x; 1.0213x over previous
//
#include <hip/hip_runtime.h>
#include <hip/hip_bf16.h>

#define N_NODES   50000
#define N_USERS   20000
#define N_EDGES   800000
#define DIM       256
#define NHEAD     8
#define DKH       32
#define NBLK_SCAN ((N_NODES + 255) / 256)   // 196

typedef __attribute__((ext_vector_type(8))) short bf16x8;
typedef __attribute__((ext_vector_type(4))) float f32x4;
typedef __attribute__((ext_vector_type(4))) unsigned short u16x4;
typedef __attribute__((ext_vector_type(8))) unsigned short u16x8;

__device__ inline unsigned short f2bf(float f) {
    union { __hip_bfloat16 b; unsigned short u; } cv;
    cv.b = __float2bfloat16(f);
    return cv.u;
}
__device__ inline float bf2f(unsigned short u) {
    return __uint_as_float(((unsigned int)u) << 16);
}

// ---------------- weight cast: fp32 -> bf16 ----------------
__global__ void cast_w_kernel(const float* __restrict__ Wq, const float* __restrict__ Wk,
                              const float* __restrict__ Wv, const float* __restrict__ Wo,
                              unsigned short* __restrict__ Wb)
{
    int gid = blockIdx.x * blockDim.x + threadIdx.x;
    if (gid >= 65536) return;
    const float* srcs[4] = { Wq, Wk, Wv, Wo };
    int m = gid >> 14;
    int off = (gid & 16383) * 4;
    float4 v = *(const float4*)(srcs[m] + off);
    u16x4 o = { f2bf(v.x), f2bf(v.y), f2bf(v.z), f2bf(v.w) };
    *(u16x4*)(Wb + (size_t)m * 65536 + off) = o;
}

// ---------------- GEMM building blocks ----------------
// LDS: A-tile only, row-major [128][512B], byte swizzle cb = c ^ ((row&7)<<4). 64 KB.

__device__ __forceinline__ void stage_a_f32(const float* __restrict__ Alo,
                                            const float* __restrict__ Ahi,
                                            int split, int row0, int M,
                                            unsigned short* Asm, int tid)
{
    #pragma unroll
    for (int it = 0; it < 16; ++it) {
        int o = it * 4096 + tid * 16;
        int r = o >> 9;
        int ce = (o & 511) >> 1;
        int ga = row0 + r; if (ga >= M) ga = M - 1;
        const float* src = ((ga < split) ? Alo + (size_t)ga * DIM
                                         : Ahi + (size_t)(ga - split) * DIM) + ce;
        float4 f0 = *(const float4*)src;
        float4 f1 = *(const float4*)(src + 4);
        u16x8 hv = { f2bf(f0.x), f2bf(f0.y), f2bf(f0.z), f2bf(f0.w),
                     f2bf(f1.x), f2bf(f1.y), f2bf(f1.z), f2bf(f1.w) };
        int cb = (o & 511) ^ ((r & 7) << 4);
        *(u16x8*)((char*)Asm + r * 512 + cb) = hv;
    }
}

__device__ __forceinline__ void stage_bf16_lds(const unsigned short* __restrict__ S,
                                               int row0, int M,
                                               unsigned short* Lsm, int tid, int wid)
{
    #pragma unroll
    for (int it = 0; it < 16; ++it) {
        int o = it * 4096 + tid * 16;
        int r = o >> 9;
        int cb = (o & 511) ^ ((r & 7) << 4);
        int ga = row0 + r;
        if (ga >= M) ga = M - 1;
        const char* src = (const char*)S + ((size_t)ga << 9) + cb;
        __builtin_amdgcn_global_load_lds(
            (const __attribute__((address_space(1))) unsigned int*)src,
            (__attribute__((address_space(3))) unsigned int*)((char*)Lsm + it * 4096 + wid * 1024),
            16, 0, 0);
    }
}

// A from LDS (swizzled), B fragments straight from global W (L2-resident, reused 4x)
__device__ __forceinline__ void mfma_core_gw(const unsigned short* Asm,
                                             const unsigned short* __restrict__ W,
                                             int col0, f32x4 acc[4][4], int lane, int wid)
{
    const int wm = wid >> 1, wn = wid & 1;
    const int lr = lane & 15, lk = lane >> 4;
    #pragma unroll
    for (int ks = 0; ks < 8; ++ks) {
        bf16x8 a[4], b[4];
        #pragma unroll
        for (int j = 0; j < 4; ++j) {
            int r = col0 + wn * 64 + j * 16 + lr;
            b[j] = *(const bf16x8*)(W + (size_t)r * 256 + ks * 32 + lk * 8);
        }
        #pragma unroll
        for (int i = 0; i < 4; ++i) {
            int r = wm * 64 + i * 16 + lr;
            int cb = (ks * 64 + lk * 16) ^ ((r & 7) << 4);
            a[i] = *(const bf16x8*)((const char*)Asm + r * 512 + cb);
        }
        #pragma unroll
        for (int i = 0; i < 4; ++i)
            #pragma unroll
            for (int j = 0; j < 4; ++j)
                acc[i][j] = __builtin_amdgcn_mfma_f32_16x16x32_bf16(a[i], b[j], acc[i][j], 0, 0, 0);
    }
}

// Epilogue MODE: 0 = fp32 linear, 1 = bf16 linear, 2 = KV K-half, 3 = KV V-half
template<int MODE>
__device__ __forceinline__ void epilogue(f32x4 acc[4][4], const float* bias, void* Cv,
                                         int row0, int col0, int M, int lane, int wid)
{
    const int wm = wid >> 1, wn = wid & 1;
    const int lr = lane & 15, lk = lane >> 4;
    float* Cf = (float*)Cv;
    unsigned short* Cb = (unsigned short*)Cv;
    #pragma unroll
    for (int i = 0; i < 4; ++i) {
        #pragma unroll
        for (int r = 0; r < 4; ++r) {
            int grow = row0 + wm * 64 + i * 16 + lk * 4 + r;
            if (grow >= M) continue;
            #pragma unroll
            for (int j = 0; j < 4; ++j) {
                int gcol = col0 + wn * 64 + j * 16 + lr;
                float val = acc[i][j][r] + bias[gcol];
                if constexpr (MODE == 0) {
                    Cf[(size_t)grow * 256 + gcol] = val;
                } else if constexpr (MODE == 1) {
                    Cb[(size_t)grow * 256 + gcol] = f2bf(val);
                } else if constexpr (MODE == 2) {
                    Cb[(size_t)grow * 512 + ((gcol >> 2) << 3) + (gcol & 3)] = f2bf(val);
                } else {
                    Cb[(size_t)grow * 512 + ((gcol >> 2) << 3) + (gcol & 3) + 4] = f2bf(val);
                }
            }
        }
    }
}

// Fused Q/K/V GEMM. grid.y in [0,6): mat = y>>1 (0:Q,1:K,2:V), col0 = (y&1)*128
__global__ __launch_bounds__(256) void gemm_qkv_kernel(
    const float* __restrict__ user, const float* __restrict__ item,
    const float* __restrict__ x,
    const unsigned short* __restrict__ Wb,   // [Wq|Wk|Wv|Wo] each 65536
    const float* __restrict__ bq, const float* __restrict__ bk, const float* __restrict__ bv,
    unsigned short* __restrict__ Qb, unsigned short* __restrict__ KVb, int M)
{
    __shared__ unsigned short Asm[128 * 256];
    const int tid = threadIdx.x;
    const int lane = tid & 63, wid = tid >> 6;
    const int row0 = blockIdx.x * 128;
    const int mat  = blockIdx.y >> 1;
    const int col0 = (blockIdx.y & 1) * 128;

    if (mat == 2) stage_a_f32(x, x, M, row0, M, Asm, tid);
    else          stage_a_f32(user, item, N_USERS, row0, M, Asm, tid);
    __syncthreads();

    f32x4 acc[4][4];
    #pragma unroll
    for (int i = 0; i < 4; ++i)
        #pragma unroll
        for (int j = 0; j < 4; ++j) acc[i][j] = (f32x4){0.f, 0.f, 0.f, 0.f};

    mfma_core_gw(Asm, Wb + (size_t)mat * 65536, col0, acc, lane, wid);

    if (mat == 0)      epilogue<1>(acc, bq, Qb,  row0, col0, M, lane, wid);
    else if (mat == 1) epilogue<2>(acc, bk, KVb, row0, col0, M, lane, wid);
    else               epilogue<3>(acc, bv, KVb, row0, col0, M, lane, wid);
}

// Final O GEMM: bf16 A via global_load_lds, W from global, fp32 out
__global__ __launch_bounds__(256) void gemm_o_kernel(
    const unsigned short* __restrict__ A,
    const unsigned short* __restrict__ Wob, const float* __restrict__ bo,
    float* __restrict__ C, int M)
{
    __shared__ unsigned short Asm[128 * 256];
    const int tid = threadIdx.x;
    const int lane = tid & 63, wid = tid >> 6;
    const int row0 = blockIdx.x * 128;
    const int col0 = blockIdx.y * 128;

    stage_bf16_lds(A, row0, M, Asm, tid, wid);
    __syncthreads();

    f32x4 acc[4][4];
    #pragma unroll
    for (int i = 0; i < 4; ++i)
        #pragma unroll
        for (int j = 0; j < 4; ++j) acc[i][j] = (f32x4){0.f, 0.f, 0.f, 0.f};

    mfma_core_gw(Asm, Wob, col0, acc, lane, wid);
    epilogue<0>(acc, bo, C, row0, col0, M, lane, wid);
}

// ---------------- CSR build ----------------
__global__ void hist_kernel(const int* __restrict__ col, int* __restrict__ cnt) {
    int e = blockIdx.x * blockDim.x + threadIdx.x;
    if (e < N_EDGES) atomicAdd(&cnt[col[e]], 1);
}

__global__ __launch_bounds__(256) void scan_blk_kernel(const int* __restrict__ cnt,
                                                       int* __restrict__ offs_tmp,
                                                       int* __restrict__ bsum) {
    __shared__ int s[256];
    int b = blockIdx.x, t = threadIdx.x;
    int i = b * 256 + t;
    int v = (i < N_NODES) ? cnt[i] : 0;
    s[t] = v;
    __syncthreads();
    #pragma unroll
    for (int d = 1; d < 256; d <<= 1) {
        int u = (t >= d) ? s[t - d] : 0;
        __syncthreads();
        s[t] += u;
        __syncthreads();
    }
    if (i < N_NODES) offs_tmp[i] = s[t] - v;
    if (t == 255) bsum[b] = s[255];
}

__global__ __launch_bounds__(256) void scan_top_kernel(int* __restrict__ bsum) {
    __shared__ int s[256];
    int t = threadIdx.x;
    int v = (t < NBLK_SCAN) ? bsum[t] : 0;
    s[t] = v;
    __syncthreads();
    #pragma unroll
    for (int d = 1; d < 256; d <<= 1) {
        int u = (t >= d) ? s[t - d] : 0;
        __syncthreads();
        s[t] += u;
        __syncthreads();
    }
    if (t < NBLK_SCAN) bsum[t] = s[t] - v;
}

__global__ __launch_bounds__(256) void scan_add_kernel(const int* __restrict__ offs_tmp,
                                                       const int* __restrict__ bsum,
                                                       int* __restrict__ offs,
                                                       int* __restrict__ cursor) {
    int i = blockIdx.x * 256 + threadIdx.x;
    if (i == 0) offs[N_NODES] = N_EDGES;
    if (i >= N_NODES) return;
    int o = offs_tmp[i] + bsum[blockIdx.x];
    offs[i] = o;
    cursor[i] = o;
}

__global__ void scatter_kernel(const int* __restrict__ row, const int* __restrict__ col,
                               int* __restrict__ cursor, int* __restrict__ esrc) {
    int e = blockIdx.x * blockDim.x + threadIdx.x;
    if (e >= N_EDGES) return;
    int c = col[e];
    int p = atomicAdd(&cursor[c], 1);
    esrc[p] = row[e];
}

// ---------------- fused edge phase: one wave per destination node ----------------
// v3: 8-deep gather pipeline (static unroll -> registers), then 4, then 1.
__global__ __launch_bounds__(256) void node_fused_kernel(
    const unsigned short* __restrict__ Qb, const unsigned short* __restrict__ KVb,
    const float* __restrict__ rel,
    const int* __restrict__ offs, const int* __restrict__ esrc,
    unsigned short* __restrict__ out_aggb)
{
    const float SC = 0.17677669529663687f;  // 1/sqrt(32)
    int wid = (blockIdx.x * blockDim.x + threadIdx.x) >> 6;
    int lane = threadIdx.x & 63;
    if (wid >= N_NODES) return;
    int beg = offs[wid], end = offs[wid + 1];
    int d0 = lane * 4;
    const char* kvbase = (const char*)KVb + lane * 16;

    u16x4 qb4 = *(const u16x4*)(Qb + (size_t)wid * DIM + d0);
    float qx = bf2f(qb4[0]), qy = bf2f(qb4[1]), qz = bf2f(qb4[2]), qw = bf2f(qb4[3]);
    float4 rl = *(const float4*)(rel + d0);

    float p0 = qx * rl.x + qy * rl.y + qz * rl.z + qw * rl.w;
    p0 += __shfl_xor(p0, 1);
    p0 += __shfl_xor(p0, 2);
    p0 += __shfl_xor(p0, 4);

    float den = 0.f;
    float4 acc = make_float4(0.f, 0.f, 0.f, 0.f);

    for (int base = beg; base < end; base += 64) {
        int n = end - base; if (n > 64) n = 64;
        int idx = base + lane; if (idx >= end) idx = end - 1;
        int my = esrc[idx];
        int j = 0;
        for (; j + 8 <= n; j += 8) {
            u16x8 kk[8];
            #pragma unroll
            for (int u = 0; u < 8; ++u) {
                int r = __shfl(my, j + u);
                kk[u] = *(const u16x8*)(kvbase + (size_t)r * 1024);
            }
            float s[8];
            #pragma unroll
            for (int u = 0; u < 8; ++u)
                s[u] = qx * bf2f(kk[u][0]) + qy * bf2f(kk[u][1])
                     + qz * bf2f(kk[u][2]) + qw * bf2f(kk[u][3]);
            #pragma unroll
            for (int u = 0; u < 8; ++u) {
                s[u] += __shfl_xor(s[u], 1);
                s[u] += __shfl_xor(s[u], 2);
                s[u] += __shfl_xor(s[u], 4);
            }
            #pragma unroll
            for (int u = 0; u < 8; ++u) {
                float w = __expf((s[u] + p0) * SC);
                den += w;
                acc.x += w * bf2f(kk[u][4]); acc.y += w * bf2f(kk[u][5]);
                acc.z += w * bf2f(kk[u][6]); acc.w += w * bf2f(kk[u][7]);
            }
        }
        for (; j + 4 <= n; j += 4) {
            u16x8 kk[4];
            #pragma unroll
            for (int u = 0; u < 4; ++u) {
                int r = __shfl(my, j + u);
                kk[u] = *(const u16x8*)(kvbase + (size_t)r * 1024);
            }
            float s[4];
            #pragma unroll
            for (int u = 0; u < 4; ++u)
                s[u] = qx * bf2f(kk[u][0]) + qy * bf2f(kk[u][1])
                     + qz * bf2f(kk[u][2]) + qw * bf2f(kk[u][3]);
            #pragma unroll
            for (int u = 0; u < 4; ++u) {
                s[u] += __shfl_xor(s[u], 1);
                s[u] += __shfl_xor(s[u], 2);
                s[u] += __shfl_xor(s[u], 4);
            }
            #pragma unroll
            for (int u = 0; u < 4; ++u) {
                float w = __expf((s[u] + p0) * SC);
                den += w;
                acc.x += w * bf2f(kk[u][4]); acc.y += w * bf2f(kk[u][5]);
                acc.z += w * bf2f(kk[u][6]); acc.w += w * bf2f(kk[u][7]);
            }
        }
        for (; j < n; ++j) {
            int r = __shfl(my, j);
            u16x8 k0 = *(const u16x8*)(kvbase + (size_t)r * 1024);
            float s0 = qx * bf2f(k0[0]) + qy * bf2f(k0[1]) + qz * bf2f(k0[2]) + qw * bf2f(k0[3]);
            s0 += __shfl_xor(s0, 1);
            s0 += __shfl_xor(s0, 2);
            s0 += __shfl_xor(s0, 4);
            float w0 = __expf((s0 + p0) * SC);
            den += w0;
            acc.x += w0 * bf2f(k0[4]); acc.y += w0 * bf2f(k0[5]);
            acc.z += w0 * bf2f(k0[6]); acc.w += w0 * bf2f(k0[7]);
        }
    }
    float rden = (end > beg) ? 1.f / den : 0.f;
    u16x4 o = { f2bf(acc.x * rden), f2bf(acc.y * rden),
                f2bf(acc.z * rden), f2bf(acc.w * rden) };
    *(u16x4*)(out_aggb + (size_t)wid * DIM + d0) = o;
}

extern "C" void kernel_launch(void* const* d_in, const int* in_sizes, int n_in,
                              void* d_out, int out_size, void* d_ws, size_t ws_size,
                              hipStream_t stream) {
    const float* x    = (const float*)d_in[0];
    const int*   row  = (const int*)d_in[1];
    const int*   col  = (const int*)d_in[2];
    const float* rel  = (const float*)d_in[3];
    const float* user = (const float*)d_in[4];
    const float* item = (const float*)d_in[5];
    const float* Wq   = (const float*)d_in[6];
    const float* bq   = (const float*)d_in[7];
    const float* Wk   = (const float*)d_in[8];
    const float* bk   = (const float*)d_in[9];
    const float* Wv   = (const float*)d_in[10];
    const float* bv   = (const float*)d_in[11];
    const float* Wo   = (const float*)d_in[12];
    const float* bo   = (const float*)d_in[13];

    char* ws = (char*)d_ws;
    size_t off = 0;
    auto alloc = [&](size_t bytes) -> void* {
        void* p = ws + off;
        off = (off + bytes + 255) & ~(size_t)255;
        return p;
    };
    unsigned short* Qb       = (unsigned short*)alloc((size_t)N_NODES * DIM * 2);
    unsigned short* KVb      = (unsigned short*)alloc((size_t)N_NODES * DIM * 2 * 2);
    unsigned short* out_aggb = (unsigned short*)alloc((size_t)N_NODES * DIM * 2);
    unsigned short* Wb       = (unsigned short*)alloc((size_t)4 * 65536 * 2);
    int*   cnt      = (int*)alloc((size_t)N_NODES * 4);
    int*   offs     = (int*)alloc((size_t)(N_NODES + 1) * 4);
    int*   offs_tmp = (int*)alloc((size_t)N_NODES * 4);
    int*   bsum     = (int*)alloc((size_t)NBLK_SCAN * 4);
    int*   esrc     = (int*)alloc((size_t)N_EDGES * 4);

    unsigned short* Wob = Wb + 196608;

    hipMemsetAsync(cnt, 0, (size_t)N_NODES * 4, stream);

    cast_w_kernel<<<(65536 + 255) / 256, 256, 0, stream>>>(Wq, Wk, Wv, Wo, Wb);
    hist_kernel<<<(N_EDGES + 255) / 256, 256, 0, stream>>>(col, cnt);
    scan_blk_kernel<<<NBLK_SCAN, 256, 0, stream>>>(cnt, offs_tmp, bsum);
    scan_top_kernel<<<1, 256, 0, stream>>>(bsum);
    scan_add_kernel<<<NBLK_SCAN, 256, 0, stream>>>(offs_tmp, bsum, offs, cnt);
    scatter_kernel<<<(N_EDGES + 255) / 256, 256, 0, stream>>>(row, col, cnt, esrc);

    const int gx = (N_NODES + 127) / 128;
    gemm_qkv_kernel<<<dim3(gx, 6), 256, 0, stream>>>(user, item, x, Wb, bq, bk, bv,
                                                     Qb, KVb, N_NODES);

    node_fused_kernel<<<(N_NODES * 64 + 255) / 256, 256, 0, stream>>>(
        Qb, KVb, rel, offs, esrc, out_aggb);

    gemm_o_kernel<<<dim3(gx, 2), 256, 0, stream>>>(out_aggb, Wob, bo, (float*)d_out, N_NODES);
}

// Round 7
// 328.429 us; speedup vs baseline: 10.4183x; 1.0742x over previous
//
#include <hip/hip_runtime.h>
#include <hip/hip_bf16.h>

#define N_NODES   50000
#define N_USERS   20000
#define N_EDGES   800000
#define DIM       256
#define NHEAD     8
#define DKH       32
#define NBLK_SCAN ((N_NODES + 255) / 256)   // 196
#define NGRP      (N_NODES / 16)            // 3125 row groups (50000 = 16*3125)
#define NGRP_PAD  3128                      // cover tile overrun to 50048
#define SLOTS_NODE (NGRP * 8 * 64)          // 1.6M fragment slots per node matrix

typedef __attribute__((ext_vector_type(8))) short bf16x8;
typedef __attribute__((ext_vector_type(4))) float f32x4;
typedef __attribute__((ext_vector_type(4))) unsigned short u16x4;
typedef __attribute__((ext_vector_type(8))) unsigned short u16x8;

__device__ inline unsigned short f2bf(float f) {
    union { __hip_bfloat16 b; unsigned short u; } cv;
    cv.b = __float2bfloat16(f);
    return cv.u;
}
__device__ inline float bf2f(unsigned short u) {
    return __uint_as_float(((unsigned int)u) << 16);
}

// Fragment-tiled layout: elem (r, d) -> ((r>>4)*8 + (d>>5))*512 + ((d>>3)&3)*128 + (r&15)*8 + (d&7)
// i.e. slot (g, ks, lane) holds rows g*16+(lane&15), k = ks*32 + (lane>>4)*8 .. +8.
// A fragment load for MFMA is then exactly 64 lanes * 8 bf16 contiguous = 1KB coalesced.

// ---------------- casts: fp32 -> fragment-tiled bf16 ----------------
__global__ void cast_inputs_kernel(const float* __restrict__ x,
                                   const float* __restrict__ user,
                                   const float* __restrict__ item,
                                   unsigned short* __restrict__ xb2,
                                   unsigned short* __restrict__ tb2)
{
    int slot = blockIdx.x * blockDim.x + threadIdx.x;
    if (slot >= SLOTS_NODE) return;
    int lane = slot & 63, ks = (slot >> 6) & 7, g = slot >> 9;
    int r = g * 16 + (lane & 15);
    int d = ks * 32 + (lane >> 4) * 8;

    const float* sx = x + (size_t)r * DIM + d;
    float4 f0 = *(const float4*)sx, f1 = *(const float4*)(sx + 4);
    u16x8 xo = { f2bf(f0.x), f2bf(f0.y), f2bf(f0.z), f2bf(f0.w),
                 f2bf(f1.x), f2bf(f1.y), f2bf(f1.z), f2bf(f1.w) };
    *(u16x8*)(xb2 + (size_t)slot * 8) = xo;

    const float* st = (r < N_USERS) ? user + (size_t)r * DIM + d
                                    : item + (size_t)(r - N_USERS) * DIM + d;
    float4 t0 = *(const float4*)st, t1 = *(const float4*)(st + 4);
    u16x8 to = { f2bf(t0.x), f2bf(t0.y), f2bf(t0.z), f2bf(t0.w),
                 f2bf(t1.x), f2bf(t1.y), f2bf(t1.z), f2bf(t1.w) };
    *(u16x8*)(tb2 + (size_t)slot * 8) = to;
}

__global__ void cast_w_kernel(const float* __restrict__ Wq, const float* __restrict__ Wk,
                              const float* __restrict__ Wv, const float* __restrict__ Wo,
                              unsigned short* __restrict__ Wb2)
{
    int gid = blockIdx.x * blockDim.x + threadIdx.x;   // 4 * 8192 slots
    if (gid >= 32768) return;
    const float* srcs[4] = { Wq, Wk, Wv, Wo };
    int m = gid >> 13, slot = gid & 8191;
    int lane = slot & 63, ks = (slot >> 6) & 7, g = slot >> 9;
    int c = g * 16 + (lane & 15);
    int d = ks * 32 + (lane >> 4) * 8;
    const float* s = srcs[m] + (size_t)c * DIM + d;
    float4 f0 = *(const float4*)s, f1 = *(const float4*)(s + 4);
    u16x8 o = { f2bf(f0.x), f2bf(f0.y), f2bf(f0.z), f2bf(f0.w),
                f2bf(f1.x), f2bf(f1.y), f2bf(f1.z), f2bf(f1.w) };
    *(u16x8*)(Wb2 + (size_t)m * 65536 + (size_t)slot * 8) = o;
}

// ---------------- register-direct MFMA GEMM core (no LDS, no barriers) ----------------
__device__ __forceinline__ void mfma_core_reg(const unsigned short* __restrict__ A2,
                                              const unsigned short* __restrict__ W2,
                                              int row0, int col0, f32x4 acc[4][4],
                                              int lane, int wid)
{
    const int gA = (row0 >> 4) + (wid >> 1) * 4;   // wm = wid>>1
    const int gB = (col0 >> 4) + (wid & 1) * 4;    // wn = wid&1
    #pragma unroll
    for (int ks = 0; ks < 8; ++ks) {
        bf16x8 a[4], b[4];
        #pragma unroll
        for (int i = 0; i < 4; ++i)
            a[i] = *(const bf16x8*)(A2 + (size_t)((gA + i) * 8 + ks) * 512 + lane * 8);
        #pragma unroll
        for (int j = 0; j < 4; ++j)
            b[j] = *(const bf16x8*)(W2 + (size_t)((gB + j) * 8 + ks) * 512 + lane * 8);
        #pragma unroll
        for (int i = 0; i < 4; ++i)
            #pragma unroll
            for (int j = 0; j < 4; ++j)
                acc[i][j] = __builtin_amdgcn_mfma_f32_16x16x32_bf16(a[i], b[j], acc[i][j], 0, 0, 0);
    }
}

// Epilogue MODE: 0 = fp32 linear, 1 = bf16 linear, 2 = KV K-half, 3 = KV V-half
template<int MODE>
__device__ __forceinline__ void epilogue(f32x4 acc[4][4], const float* bias, void* Cv,
                                         int row0, int col0, int M, int lane, int wid)
{
    const int wm = wid >> 1, wn = wid & 1;
    const int lr = lane & 15, lk = lane >> 4;
    float* Cf = (float*)Cv;
    unsigned short* Cb = (unsigned short*)Cv;
    #pragma unroll
    for (int i = 0; i < 4; ++i) {
        #pragma unroll
        for (int r = 0; r < 4; ++r) {
            int grow = row0 + wm * 64 + i * 16 + lk * 4 + r;
            if (grow >= M) continue;
            #pragma unroll
            for (int j = 0; j < 4; ++j) {
                int gcol = col0 + wn * 64 + j * 16 + lr;
                float val = acc[i][j][r] + bias[gcol];
                if constexpr (MODE == 0) {
                    Cf[(size_t)grow * 256 + gcol] = val;
                } else if constexpr (MODE == 1) {
                    Cb[(size_t)grow * 256 + gcol] = f2bf(val);
                } else if constexpr (MODE == 2) {
                    Cb[(size_t)grow * 512 + ((gcol >> 2) << 3) + (gcol & 3)] = f2bf(val);
                } else {
                    Cb[(size_t)grow * 512 + ((gcol >> 2) << 3) + (gcol & 3) + 4] = f2bf(val);
                }
            }
        }
    }
}

// Fused Q/K/V GEMM, register-direct. grid.y in [0,6): mat = y>>1 (0:Q,1:K,2:V), col0 = (y&1)*128
__global__ __launch_bounds__(256) void gemm_qkv_reg(
    const unsigned short* __restrict__ tb2, const unsigned short* __restrict__ xb2,
    const unsigned short* __restrict__ Wb2,
    const float* __restrict__ bq, const float* __restrict__ bk, const float* __restrict__ bv,
    unsigned short* __restrict__ Qb, unsigned short* __restrict__ KVb, int M)
{
    const int tid = threadIdx.x;
    const int lane = tid & 63, wid = tid >> 6;
    const int row0 = blockIdx.x * 128;
    const int mat  = blockIdx.y >> 1;
    const int col0 = (blockIdx.y & 1) * 128;

    const unsigned short* A2 = (mat == 2) ? xb2 : tb2;
    const unsigned short* W2 = Wb2 + (size_t)mat * 65536;

    f32x4 acc[4][4];
    #pragma unroll
    for (int i = 0; i < 4; ++i)
        #pragma unroll
        for (int j = 0; j < 4; ++j) acc[i][j] = (f32x4){0.f, 0.f, 0.f, 0.f};

    mfma_core_reg(A2, W2, row0, col0, acc, lane, wid);

    if (mat == 0)      epilogue<1>(acc, bq, Qb,  row0, col0, M, lane, wid);
    else if (mat == 1) epilogue<2>(acc, bk, KVb, row0, col0, M, lane, wid);
    else               epilogue<3>(acc, bv, KVb, row0, col0, M, lane, wid);
}

// Final O GEMM: tiled bf16 A (from node kernel), fp32 out
__global__ __launch_bounds__(256) void gemm_o_reg(
    const unsigned short* __restrict__ A2,
    const unsigned short* __restrict__ Wb2, const float* __restrict__ bo,
    float* __restrict__ C, int M)
{
    const int tid = threadIdx.x;
    const int lane = tid & 63, wid = tid >> 6;
    const int row0 = blockIdx.x * 128;
    const int col0 = blockIdx.y * 128;

    f32x4 acc[4][4];
    #pragma unroll
    for (int i = 0; i < 4; ++i)
        #pragma unroll
        for (int j = 0; j < 4; ++j) acc[i][j] = (f32x4){0.f, 0.f, 0.f, 0.f};

    mfma_core_reg(A2, Wb2 + 3 * 65536, row0, col0, acc, lane, wid);
    epilogue<0>(acc, bo, C, row0, col0, M, lane, wid);
}

// ---------------- CSR build ----------------
__global__ void hist_kernel(const int* __restrict__ col, int* __restrict__ cnt) {
    int e = blockIdx.x * blockDim.x + threadIdx.x;
    if (e < N_EDGES) atomicAdd(&cnt[col[e]], 1);
}

__global__ __launch_bounds__(256) void scan_blk_kernel(const int* __restrict__ cnt,
                                                       int* __restrict__ offs_tmp,
                                                       int* __restrict__ bsum) {
    __shared__ int s[256];
    int b = blockIdx.x, t = threadIdx.x;
    int i = b * 256 + t;
    int v = (i < N_NODES) ? cnt[i] : 0;
    s[t] = v;
    __syncthreads();
    #pragma unroll
    for (int d = 1; d < 256; d <<= 1) {
        int u = (t >= d) ? s[t - d] : 0;
        __syncthreads();
        s[t] += u;
        __syncthreads();
    }
    if (i < N_NODES) offs_tmp[i] = s[t] - v;
    if (t == 255) bsum[b] = s[255];
}

__global__ __launch_bounds__(256) void scan_top_kernel(int* __restrict__ bsum) {
    __shared__ int s[256];
    int t = threadIdx.x;
    int v = (t < NBLK_SCAN) ? bsum[t] : 0;
    s[t] = v;
    __syncthreads();
    #pragma unroll
    for (int d = 1; d < 256; d <<= 1) {
        int u = (t >= d) ? s[t - d] : 0;
        __syncthreads();
        s[t] += u;
        __syncthreads();
    }
    if (t < NBLK_SCAN) bsum[t] = s[t] - v;
}

__global__ __launch_bounds__(256) void scan_add_kernel(const int* __restrict__ offs_tmp,
                                                       const int* __restrict__ bsum,
                                                       int* __restrict__ offs,
                                                       int* __restrict__ cursor) {
    int i = blockIdx.x * 256 + threadIdx.x;
    if (i == 0) offs[N_NODES] = N_EDGES;
    if (i >= N_NODES) return;
    int o = offs_tmp[i] + bsum[blockIdx.x];
    offs[i] = o;
    cursor[i] = o;
}

__global__ void scatter_kernel(const int* __restrict__ row, const int* __restrict__ col,
                               int* __restrict__ cursor, int* __restrict__ esrc) {
    int e = blockIdx.x * blockDim.x + threadIdx.x;
    if (e >= N_EDGES) return;
    int c = col[e];
    int p = atomicAdd(&cursor[c], 1);
    esrc[p] = row[e];
}

// ---------------- fused edge phase: one wave per destination node ----------------
// 8-deep gather pipeline; output written in fragment-tiled layout for the O-GEMM.
__global__ __launch_bounds__(256) void node_fused_kernel(
    const unsigned short* __restrict__ Qb, const unsigned short* __restrict__ KVb,
    const float* __restrict__ rel,
    const int* __restrict__ offs, const int* __restrict__ esrc,
    unsigned short* __restrict__ outagg2)
{
    const float SC = 0.17677669529663687f;  // 1/sqrt(32)
    int wid = (blockIdx.x * blockDim.x + threadIdx.x) >> 6;
    int lane = threadIdx.x & 63;
    if (wid >= N_NODES) return;
    int beg = offs[wid], end = offs[wid + 1];
    int d0 = lane * 4;
    const char* kvbase = (const char*)KVb + lane * 16;

    u16x4 qb4 = *(const u16x4*)(Qb + (size_t)wid * DIM + d0);
    float qx = bf2f(qb4[0]), qy = bf2f(qb4[1]), qz = bf2f(qb4[2]), qw = bf2f(qb4[3]);
    float4 rl = *(const float4*)(rel + d0);

    float p0 = qx * rl.x + qy * rl.y + qz * rl.z + qw * rl.w;
    p0 += __shfl_xor(p0, 1);
    p0 += __shfl_xor(p0, 2);
    p0 += __shfl_xor(p0, 4);

    float den = 0.f;
    float4 acc = make_float4(0.f, 0.f, 0.f, 0.f);

    for (int base = beg; base < end; base += 64) {
        int n = end - base; if (n > 64) n = 64;
        int idx = base + lane; if (idx >= end) idx = end - 1;
        int my = esrc[idx];
        int j = 0;
        for (; j + 8 <= n; j += 8) {
            u16x8 kk[8];
            #pragma unroll
            for (int u = 0; u < 8; ++u) {
                int r = __shfl(my, j + u);
                kk[u] = *(const u16x8*)(kvbase + (size_t)r * 1024);
            }
            float s[8];
            #pragma unroll
            for (int u = 0; u < 8; ++u)
                s[u] = qx * bf2f(kk[u][0]) + qy * bf2f(kk[u][1])
                     + qz * bf2f(kk[u][2]) + qw * bf2f(kk[u][3]);
            #pragma unroll
            for (int u = 0; u < 8; ++u) {
                s[u] += __shfl_xor(s[u], 1);
                s[u] += __shfl_xor(s[u], 2);
                s[u] += __shfl_xor(s[u], 4);
            }
            #pragma unroll
            for (int u = 0; u < 8; ++u) {
                float w = __expf((s[u] + p0) * SC);
                den += w;
                acc.x += w * bf2f(kk[u][4]); acc.y += w * bf2f(kk[u][5]);
                acc.z += w * bf2f(kk[u][6]); acc.w += w * bf2f(kk[u][7]);
            }
        }
        for (; j + 4 <= n; j += 4) {
            u16x8 kk[4];
            #pragma unroll
            for (int u = 0; u < 4; ++u) {
                int r = __shfl(my, j + u);
                kk[u] = *(const u16x8*)(kvbase + (size_t)r * 1024);
            }
            float s[4];
            #pragma unroll
            for (int u = 0; u < 4; ++u)
                s[u] = qx * bf2f(kk[u][0]) + qy * bf2f(kk[u][1])
                     + qz * bf2f(kk[u][2]) + qw * bf2f(kk[u][3]);
            #pragma unroll
            for (int u = 0; u < 4; ++u) {
                s[u] += __shfl_xor(s[u], 1);
                s[u] += __shfl_xor(s[u], 2);
                s[u] += __shfl_xor(s[u], 4);
            }
            #pragma unroll
            for (int u = 0; u < 4; ++u) {
                float w = __expf((s[u] + p0) * SC);
                den += w;
                acc.x += w * bf2f(kk[u][4]); acc.y += w * bf2f(kk[u][5]);
                acc.z += w * bf2f(kk[u][6]); acc.w += w * bf2f(kk[u][7]);
            }
        }
        for (; j < n; ++j) {
            int r = __shfl(my, j);
            u16x8 k0 = *(const u16x8*)(kvbase + (size_t)r * 1024);
            float s0 = qx * bf2f(k0[0]) + qy * bf2f(k0[1]) + qz * bf2f(k0[2]) + qw * bf2f(k0[3]);
            s0 += __shfl_xor(s0, 1);
            s0 += __shfl_xor(s0, 2);
            s0 += __shfl_xor(s0, 4);
            float w0 = __expf((s0 + p0) * SC);
            den += w0;
            acc.x += w0 * bf2f(k0[4]); acc.y += w0 * bf2f(k0[5]);
            acc.z += w0 * bf2f(k0[6]); acc.w += w0 * bf2f(k0[7]);
        }
    }
    float rden = (end > beg) ? 1.f / den : 0.f;
    u16x4 o = { f2bf(acc.x * rden), f2bf(acc.y * rden),
                f2bf(acc.z * rden), f2bf(acc.w * rden) };
    // fragment-tiled write: d0 = lane*4 -> ks = lane>>3, lk = (lane>>1)&3, e = (lane&1)*4
    int ks = lane >> 3, lk = (lane >> 1) & 3, e4 = (lane & 1) * 4;
    size_t toff = ((size_t)(wid >> 4) * 8 + ks) * 512 + (lk * 16 + (wid & 15)) * 8 + e4;
    *(u16x4*)(outagg2 + toff) = o;
}

extern "C" void kernel_launch(void* const* d_in, const int* in_sizes, int n_in,
                              void* d_out, int out_size, void* d_ws, size_t ws_size,
                              hipStream_t stream) {
    const float* x    = (const float*)d_in[0];
    const int*   row  = (const int*)d_in[1];
    const int*   col  = (const int*)d_in[2];
    const float* rel  = (const float*)d_in[3];
    const float* user = (const float*)d_in[4];
    const float* item = (const float*)d_in[5];
    const float* Wq   = (const float*)d_in[6];
    const float* bq   = (const float*)d_in[7];
    const float* Wk   = (const float*)d_in[8];
    const float* bk   = (const float*)d_in[9];
    const float* Wv   = (const float*)d_in[10];
    const float* bv   = (const float*)d_in[11];
    const float* Wo   = (const float*)d_in[12];
    const float* bo   = (const float*)d_in[13];

    char* ws = (char*)d_ws;
    size_t off = 0;
    auto alloc = [&](size_t bytes) -> void* {
        void* p = ws + off;
        off = (off + bytes + 255) & ~(size_t)255;
        return p;
    };
    const size_t tiled_sz = (size_t)NGRP_PAD * 4096 * 2;   // padded fragment-tiled node matrix
    unsigned short* Qb      = (unsigned short*)alloc((size_t)N_NODES * DIM * 2);
    unsigned short* KVb     = (unsigned short*)alloc((size_t)N_NODES * DIM * 2 * 2);
    unsigned short* xb2     = (unsigned short*)alloc(tiled_sz);
    unsigned short* tb2     = (unsigned short*)alloc(tiled_sz);
    unsigned short* outagg2 = (unsigned short*)alloc(tiled_sz);
    unsigned short* Wb2     = (unsigned short*)alloc((size_t)4 * 65536 * 2);
    int*   cnt      = (int*)alloc((size_t)N_NODES * 4);
    int*   offs     = (int*)alloc((size_t)(N_NODES + 1) * 4);
    int*   offs_tmp = (int*)alloc((size_t)N_NODES * 4);
    int*   bsum     = (int*)alloc((size_t)NBLK_SCAN * 4);
    int*   esrc     = (int*)alloc((size_t)N_EDGES * 4);

    hipMemsetAsync(cnt, 0, (size_t)N_NODES * 4, stream);

    cast_w_kernel<<<(32768 + 255) / 256, 256, 0, stream>>>(Wq, Wk, Wv, Wo, Wb2);
    cast_inputs_kernel<<<(SLOTS_NODE + 255) / 256, 256, 0, stream>>>(x, user, item, xb2, tb2);

    hist_kernel<<<(N_EDGES + 255) / 256, 256, 0, stream>>>(col, cnt);
    scan_blk_kernel<<<NBLK_SCAN, 256, 0, stream>>>(cnt, offs_tmp, bsum);
    scan_top_kernel<<<1, 256, 0, stream>>>(bsum);
    scan_add_kernel<<<NBLK_SCAN, 256, 0, stream>>>(offs_tmp, bsum, offs, cnt);
    scatter_kernel<<<(N_EDGES + 255) / 256, 256, 0, stream>>>(row, col, cnt, esrc);

    const int gx = (N_NODES + 127) / 128;
    gemm_qkv_reg<<<dim3(gx, 6), 256, 0, stream>>>(tb2, xb2, Wb2, bq, bk, bv, Qb, KVb, N_NODES);

    node_fused_kernel<<<(N_NODES * 64 + 255) / 256, 256, 0, stream>>>(
        Qb, KVb, rel, offs, esrc, outagg2);

    gemm_o_reg<<<dim3(gx, 2), 256, 0, stream>>>(outagg2, Wb2, bo, (float*)d_out, N_NODES);
}

// Round 8
// 285.925 us; speedup vs baseline: 11.9671x; 1.1487x over previous
//
#include <hip/hip_runtime.h>
#include <hip/hip_bf16.h>

#define N_NODES   50000
#define N_USERS   20000
#define N_EDGES   800000
#define DIM       256
#define NHEAD     8
#define DKH       32
#define NBLK_SCAN ((N_NODES + 255) / 256)   // 196
#define NGRP      (N_NODES / 16)            // 3125 row groups (50000 = 16*3125)
#define NGRP_PAD  3128                      // cover tile overrun to 50048
#define SLOTS_NODE (NGRP * 8 * 64)          // 1.6M fragment slots per node matrix
#define KVROW     768                       // 256B K-fp8 + 512B V-bf16

typedef __attribute__((ext_vector_type(8))) short bf16x8;
typedef __attribute__((ext_vector_type(4))) float f32x4;
typedef __attribute__((ext_vector_type(4))) unsigned short u16x4;
typedef __attribute__((ext_vector_type(8))) unsigned short u16x8;

__device__ inline unsigned short f2bf(float f) {
    union { __hip_bfloat16 b; unsigned short u; } cv;
    cv.b = __float2bfloat16(f);
    return cv.u;
}
__device__ inline float bf2f(unsigned short u) {
    return __uint_as_float(((unsigned int)u) << 16);
}
__device__ inline unsigned char f2fp8(float f) {
    // OCP e4m3 via HW pack (gfx950)
    unsigned int p = __builtin_amdgcn_cvt_pk_fp8_f32(f, f, 0, false);
    return (unsigned char)(p & 0xff);
}

// Fragment-tiled layout: elem (r, d) -> ((r>>4)*8 + (d>>5))*512 + ((d>>3)&3)*128 + (r&15)*8 + (d&7)
// A fragment load for MFMA is then exactly 64 lanes * 8 bf16 contiguous = 1KB coalesced.

// ---------------- casts: fp32 -> fragment-tiled bf16 ----------------
__global__ void cast_inputs_kernel(const float* __restrict__ x,
                                   const float* __restrict__ user,
                                   const float* __restrict__ item,
                                   unsigned short* __restrict__ xb2,
                                   unsigned short* __restrict__ tb2)
{
    int slot = blockIdx.x * blockDim.x + threadIdx.x;
    if (slot >= SLOTS_NODE) return;
    int lane = slot & 63, ks = (slot >> 6) & 7, g = slot >> 9;
    int r = g * 16 + (lane & 15);
    int d = ks * 32 + (lane >> 4) * 8;

    const float* sx = x + (size_t)r * DIM + d;
    float4 f0 = *(const float4*)sx, f1 = *(const float4*)(sx + 4);
    u16x8 xo = { f2bf(f0.x), f2bf(f0.y), f2bf(f0.z), f2bf(f0.w),
                 f2bf(f1.x), f2bf(f1.y), f2bf(f1.z), f2bf(f1.w) };
    *(u16x8*)(xb2 + (size_t)slot * 8) = xo;

    const float* st = (r < N_USERS) ? user + (size_t)r * DIM + d
                                    : item + (size_t)(r - N_USERS) * DIM + d;
    float4 t0 = *(const float4*)st, t1 = *(const float4*)(st + 4);
    u16x8 to = { f2bf(t0.x), f2bf(t0.y), f2bf(t0.z), f2bf(t0.w),
                 f2bf(t1.x), f2bf(t1.y), f2bf(t1.z), f2bf(t1.w) };
    *(u16x8*)(tb2 + (size_t)slot * 8) = to;
}

__global__ void cast_w_kernel(const float* __restrict__ Wq, const float* __restrict__ Wk,
                              const float* __restrict__ Wv, const float* __restrict__ Wo,
                              unsigned short* __restrict__ Wb2)
{
    int gid = blockIdx.x * blockDim.x + threadIdx.x;   // 4 * 8192 slots
    if (gid >= 32768) return;
    const float* srcs[4] = { Wq, Wk, Wv, Wo };
    int m = gid >> 13, slot = gid & 8191;
    int lane = slot & 63, ks = (slot >> 6) & 7, g = slot >> 9;
    int c = g * 16 + (lane & 15);
    int d = ks * 32 + (lane >> 4) * 8;
    const float* s = srcs[m] + (size_t)c * DIM + d;
    float4 f0 = *(const float4*)s, f1 = *(const float4*)(s + 4);
    u16x8 o = { f2bf(f0.x), f2bf(f0.y), f2bf(f0.z), f2bf(f0.w),
                f2bf(f1.x), f2bf(f1.y), f2bf(f1.z), f2bf(f1.w) };
    *(u16x8*)(Wb2 + (size_t)m * 65536 + (size_t)slot * 8) = o;
}

// ---------------- register-direct MFMA GEMM core (no LDS, no barriers) ----------------
__device__ __forceinline__ void mfma_core_reg(const unsigned short* __restrict__ A2,
                                              const unsigned short* __restrict__ W2,
                                              int row0, int col0, f32x4 acc[4][4],
                                              int lane, int wid)
{
    const int gA = (row0 >> 4) + (wid >> 1) * 4;   // wm = wid>>1
    const int gB = (col0 >> 4) + (wid & 1) * 4;    // wn = wid&1
    #pragma unroll
    for (int ks = 0; ks < 8; ++ks) {
        bf16x8 a[4], b[4];
        #pragma unroll
        for (int i = 0; i < 4; ++i)
            a[i] = *(const bf16x8*)(A2 + (size_t)((gA + i) * 8 + ks) * 512 + lane * 8);
        #pragma unroll
        for (int j = 0; j < 4; ++j)
            b[j] = *(const bf16x8*)(W2 + (size_t)((gB + j) * 8 + ks) * 512 + lane * 8);
        #pragma unroll
        for (int i = 0; i < 4; ++i)
            #pragma unroll
            for (int j = 0; j < 4; ++j)
                acc[i][j] = __builtin_amdgcn_mfma_f32_16x16x32_bf16(a[i], b[j], acc[i][j], 0, 0, 0);
    }
}

// Epilogue MODE: 0 = fp32 linear, 1 = bf16 linear, 2 = KV K-half (fp8), 3 = KV V-half (bf16)
template<int MODE>
__device__ __forceinline__ void epilogue(f32x4 acc[4][4], const float* bias, void* Cv,
                                         int row0, int col0, int M, int lane, int wid)
{
    const int wm = wid >> 1, wn = wid & 1;
    const int lr = lane & 15, lk = lane >> 4;
    float* Cf = (float*)Cv;
    unsigned short* Cb = (unsigned short*)Cv;
    unsigned char* C8 = (unsigned char*)Cv;
    #pragma unroll
    for (int i = 0; i < 4; ++i) {
        #pragma unroll
        for (int r = 0; r < 4; ++r) {
            int grow = row0 + wm * 64 + i * 16 + lk * 4 + r;
            if (grow >= M) continue;
            #pragma unroll
            for (int j = 0; j < 4; ++j) {
                int gcol = col0 + wn * 64 + j * 16 + lr;
                float val = acc[i][j][r] + bias[gcol];
                if constexpr (MODE == 0) {
                    Cf[(size_t)grow * 256 + gcol] = val;
                } else if constexpr (MODE == 1) {
                    Cb[(size_t)grow * 256 + gcol] = f2bf(val);
                } else if constexpr (MODE == 2) {
                    C8[(size_t)grow * KVROW + gcol] = f2fp8(val);
                } else {
                    *(unsigned short*)(C8 + (size_t)grow * KVROW + 256 + gcol * 2) = f2bf(val);
                }
            }
        }
    }
}

// Fused Q/K/V GEMM, register-direct. grid.y in [0,6): mat = y>>1 (0:Q,1:K,2:V), col0 = (y&1)*128
__global__ __launch_bounds__(256) void gemm_qkv_reg(
    const unsigned short* __restrict__ tb2, const unsigned short* __restrict__ xb2,
    const unsigned short* __restrict__ Wb2,
    const float* __restrict__ bq, const float* __restrict__ bk, const float* __restrict__ bv,
    unsigned short* __restrict__ Qb, unsigned char* __restrict__ KVb, int M)
{
    const int tid = threadIdx.x;
    const int lane = tid & 63, wid = tid >> 6;
    const int row0 = blockIdx.x * 128;
    const int mat  = blockIdx.y >> 1;
    const int col0 = (blockIdx.y & 1) * 128;

    const unsigned short* A2 = (mat == 2) ? xb2 : tb2;
    const unsigned short* W2 = Wb2 + (size_t)mat * 65536;

    f32x4 acc[4][4];
    #pragma unroll
    for (int i = 0; i < 4; ++i)
        #pragma unroll
        for (int j = 0; j < 4; ++j) acc[i][j] = (f32x4){0.f, 0.f, 0.f, 0.f};

    mfma_core_reg(A2, W2, row0, col0, acc, lane, wid);

    if (mat == 0)      epilogue<1>(acc, bq, Qb,  row0, col0, M, lane, wid);
    else if (mat == 1) epilogue<2>(acc, bk, KVb, row0, col0, M, lane, wid);
    else               epilogue<3>(acc, bv, KVb, row0, col0, M, lane, wid);
}

// Final O GEMM: tiled bf16 A (from node kernel), fp32 out
__global__ __launch_bounds__(256) void gemm_o_reg(
    const unsigned short* __restrict__ A2,
    const unsigned short* __restrict__ Wb2, const float* __restrict__ bo,
    float* __restrict__ C, int M)
{
    const int tid = threadIdx.x;
    const int lane = tid & 63, wid = tid >> 6;
    const int row0 = blockIdx.x * 128;
    const int col0 = blockIdx.y * 128;

    f32x4 acc[4][4];
    #pragma unroll
    for (int i = 0; i < 4; ++i)
        #pragma unroll
        for (int j = 0; j < 4; ++j) acc[i][j] = (f32x4){0.f, 0.f, 0.f, 0.f};

    mfma_core_reg(A2, Wb2 + 3 * 65536, row0, col0, acc, lane, wid);
    epilogue<0>(acc, bo, C, row0, col0, M, lane, wid);
}

// ---------------- CSR build ----------------
__global__ void hist_kernel(const int* __restrict__ col, int* __restrict__ cnt) {
    int e = blockIdx.x * blockDim.x + threadIdx.x;
    if (e < N_EDGES) atomicAdd(&cnt[col[e]], 1);
}

__global__ __launch_bounds__(256) void scan_blk_kernel(const int* __restrict__ cnt,
                                                       int* __restrict__ offs_tmp,
                                                       int* __restrict__ bsum) {
    __shared__ int s[256];
    int b = blockIdx.x, t = threadIdx.x;
    int i = b * 256 + t;
    int v = (i < N_NODES) ? cnt[i] : 0;
    s[t] = v;
    __syncthreads();
    #pragma unroll
    for (int d = 1; d < 256; d <<= 1) {
        int u = (t >= d) ? s[t - d] : 0;
        __syncthreads();
        s[t] += u;
        __syncthreads();
    }
    if (i < N_NODES) offs_tmp[i] = s[t] - v;
    if (t == 255) bsum[b] = s[255];
}

__global__ __launch_bounds__(256) void scan_top_kernel(int* __restrict__ bsum) {
    __shared__ int s[256];
    int t = threadIdx.x;
    int v = (t < NBLK_SCAN) ? bsum[t] : 0;
    s[t] = v;
    __syncthreads();
    #pragma unroll
    for (int d = 1; d < 256; d <<= 1) {
        int u = (t >= d) ? s[t - d] : 0;
        __syncthreads();
        s[t] += u;
        __syncthreads();
    }
    if (t < NBLK_SCAN) bsum[t] = s[t] - v;
}

__global__ __launch_bounds__(256) void scan_add_kernel(const int* __restrict__ offs_tmp,
                                                       const int* __restrict__ bsum,
                                                       int* __restrict__ offs,
                                                       int* __restrict__ cursor) {
    int i = blockIdx.x * 256 + threadIdx.x;
    if (i == 0) offs[N_NODES] = N_EDGES;
    if (i >= N_NODES) return;
    int o = offs_tmp[i] + bsum[blockIdx.x];
    offs[i] = o;
    cursor[i] = o;
}

__global__ void scatter_kernel(const int* __restrict__ row, const int* __restrict__ col,
                               int* __restrict__ cursor, int* __restrict__ esrc) {
    int e = blockIdx.x * blockDim.x + threadIdx.x;
    if (e >= N_EDGES) return;
    int c = col[e];
    int p = atomicAdd(&cursor[c], 1);
    esrc[p] = row[e];
}

// ---------------- fused edge phase: one wave per destination node ----------------
// K fp8 (4B/lane) + V bf16 (8B/lane): 768B/edge row. 8-deep gather pipeline.
__global__ __launch_bounds__(256) void node_fused_kernel(
    const unsigned short* __restrict__ Qb, const unsigned char* __restrict__ KVb,
    const float* __restrict__ rel,
    const int* __restrict__ offs, const int* __restrict__ esrc,
    unsigned short* __restrict__ outagg2)
{
    const float SC = 0.17677669529663687f;  // 1/sqrt(32)
    int wid = (blockIdx.x * blockDim.x + threadIdx.x) >> 6;
    int lane = threadIdx.x & 63;
    if (wid >= N_NODES) return;
    int beg = offs[wid], end = offs[wid + 1];
    int d0 = lane * 4;
    const unsigned char* kbase = KVb + lane * 4;
    const unsigned char* vbase = KVb + 256 + lane * 8;

    u16x4 qb4 = *(const u16x4*)(Qb + (size_t)wid * DIM + d0);
    float qx = bf2f(qb4[0]), qy = bf2f(qb4[1]), qz = bf2f(qb4[2]), qw = bf2f(qb4[3]);
    float4 rl = *(const float4*)(rel + d0);

    float p0 = qx * rl.x + qy * rl.y + qz * rl.z + qw * rl.w;
    p0 += __shfl_xor(p0, 1);
    p0 += __shfl_xor(p0, 2);
    p0 += __shfl_xor(p0, 4);

    float den = 0.f;
    float4 acc = make_float4(0.f, 0.f, 0.f, 0.f);

    for (int base = beg; base < end; base += 64) {
        int n = end - base; if (n > 64) n = 64;
        int idx = base + lane; if (idx >= end) idx = end - 1;
        int my = esrc[idx];
        int j = 0;
        for (; j + 8 <= n; j += 8) {
            unsigned int kw[8]; u16x4 vv[8];
            #pragma unroll
            for (int u = 0; u < 8; ++u) {
                int r = __shfl(my, j + u);
                size_t ro = (size_t)r * KVROW;
                kw[u] = *(const unsigned int*)(kbase + ro);
                vv[u] = *(const u16x4*)(vbase + ro);
            }
            float s[8];
            #pragma unroll
            for (int u = 0; u < 8; ++u)
                s[u] = qx * __builtin_amdgcn_cvt_f32_fp8(kw[u], 0)
                     + qy * __builtin_amdgcn_cvt_f32_fp8(kw[u], 1)
                     + qz * __builtin_amdgcn_cvt_f32_fp8(kw[u], 2)
                     + qw * __builtin_amdgcn_cvt_f32_fp8(kw[u], 3);
            #pragma unroll
            for (int u = 0; u < 8; ++u) {
                s[u] += __shfl_xor(s[u], 1);
                s[u] += __shfl_xor(s[u], 2);
                s[u] += __shfl_xor(s[u], 4);
            }
            #pragma unroll
            for (int u = 0; u < 8; ++u) {
                float w = __expf((s[u] + p0) * SC);
                den += w;
                acc.x += w * bf2f(vv[u][0]); acc.y += w * bf2f(vv[u][1]);
                acc.z += w * bf2f(vv[u][2]); acc.w += w * bf2f(vv[u][3]);
            }
        }
        for (; j + 4 <= n; j += 4) {
            unsigned int kw[4]; u16x4 vv[4];
            #pragma unroll
            for (int u = 0; u < 4; ++u) {
                int r = __shfl(my, j + u);
                size_t ro = (size_t)r * KVROW;
                kw[u] = *(const unsigned int*)(kbase + ro);
                vv[u] = *(const u16x4*)(vbase + ro);
            }
            float s[4];
            #pragma unroll
            for (int u = 0; u < 4; ++u)
                s[u] = qx * __builtin_amdgcn_cvt_f32_fp8(kw[u], 0)
                     + qy * __builtin_amdgcn_cvt_f32_fp8(kw[u], 1)
                     + qz * __builtin_amdgcn_cvt_f32_fp8(kw[u], 2)
                     + qw * __builtin_amdgcn_cvt_f32_fp8(kw[u], 3);
            #pragma unroll
            for (int u = 0; u < 4; ++u) {
                s[u] += __shfl_xor(s[u], 1);
                s[u] += __shfl_xor(s[u], 2);
                s[u] += __shfl_xor(s[u], 4);
            }
            #pragma unroll
            for (int u = 0; u < 4; ++u) {
                float w = __expf((s[u] + p0) * SC);
                den += w;
                acc.x += w * bf2f(vv[u][0]); acc.y += w * bf2f(vv[u][1]);
                acc.z += w * bf2f(vv[u][2]); acc.w += w * bf2f(vv[u][3]);
            }
        }
        for (; j < n; ++j) {
            int r = __shfl(my, j);
            size_t ro = (size_t)r * KVROW;
            unsigned int kw = *(const unsigned int*)(kbase + ro);
            u16x4 vv = *(const u16x4*)(vbase + ro);
            float s0 = qx * __builtin_amdgcn_cvt_f32_fp8(kw, 0)
                     + qy * __builtin_amdgcn_cvt_f32_fp8(kw, 1)
                     + qz * __builtin_amdgcn_cvt_f32_fp8(kw, 2)
                     + qw * __builtin_amdgcn_cvt_f32_fp8(kw, 3);
            s0 += __shfl_xor(s0, 1);
            s0 += __shfl_xor(s0, 2);
            s0 += __shfl_xor(s0, 4);
            float w0 = __expf((s0 + p0) * SC);
            den += w0;
            acc.x += w0 * bf2f(vv[0]); acc.y += w0 * bf2f(vv[1]);
            acc.z += w0 * bf2f(vv[2]); acc.w += w0 * bf2f(vv[3]);
        }
    }
    float rden = (end > beg) ? 1.f / den : 0.f;
    u16x4 o = { f2bf(acc.x * rden), f2bf(acc.y * rden),
                f2bf(acc.z * rden), f2bf(acc.w * rden) };
    // fragment-tiled write: d0 = lane*4 -> ks = lane>>3, lk = (lane>>1)&3, e = (lane&1)*4
    int ks = lane >> 3, lk = (lane >> 1) & 3, e4 = (lane & 1) * 4;
    size_t toff = ((size_t)(wid >> 4) * 8 + ks) * 512 + (lk * 16 + (wid & 15)) * 8 + e4;
    *(u16x4*)(outagg2 + toff) = o;
}

extern "C" void kernel_launch(void* const* d_in, const int* in_sizes, int n_in,
                              void* d_out, int out_size, void* d_ws, size_t ws_size,
                              hipStream_t stream) {
    const float* x    = (const float*)d_in[0];
    const int*   row  = (const int*)d_in[1];
    const int*   col  = (const int*)d_in[2];
    const float* rel  = (const float*)d_in[3];
    const float* user = (const float*)d_in[4];
    const float* item = (const float*)d_in[5];
    const float* Wq   = (const float*)d_in[6];
    const float* bq   = (const float*)d_in[7];
    const float* Wk   = (const float*)d_in[8];
    const float* bk   = (const float*)d_in[9];
    const float* Wv   = (const float*)d_in[10];
    const float* bv   = (const float*)d_in[11];
    const float* Wo   = (const float*)d_in[12];
    const float* bo   = (const float*)d_in[13];

    char* ws = (char*)d_ws;
    size_t off = 0;
    auto alloc = [&](size_t bytes) -> void* {
        void* p = ws + off;
        off = (off + bytes + 255) & ~(size_t)255;
        return p;
    };
    const size_t tiled_sz = (size_t)NGRP_PAD * 4096 * 2;
    unsigned short* Qb      = (unsigned short*)alloc((size_t)N_NODES * DIM * 2);
    unsigned char*  KVb     = (unsigned char*)alloc((size_t)N_NODES * KVROW);
    unsigned short* xb2     = (unsigned short*)alloc(tiled_sz);
    unsigned short* tb2     = (unsigned short*)alloc(tiled_sz);
    unsigned short* outagg2 = (unsigned short*)alloc(tiled_sz);
    unsigned short* Wb2     = (unsigned short*)alloc((size_t)4 * 65536 * 2);
    int*   cnt      = (int*)alloc((size_t)N_NODES * 4);
    int*   offs     = (int*)alloc((size_t)(N_NODES + 1) * 4);
    int*   offs_tmp = (int*)alloc((size_t)N_NODES * 4);
    int*   bsum     = (int*)alloc((size_t)NBLK_SCAN * 4);
    int*   esrc     = (int*)alloc((size_t)N_EDGES * 4);

    hipMemsetAsync(cnt, 0, (size_t)N_NODES * 4, stream);

    cast_w_kernel<<<(32768 + 255) / 256, 256, 0, stream>>>(Wq, Wk, Wv, Wo, Wb2);
    cast_inputs_kernel<<<(SLOTS_NODE + 255) / 256, 256, 0, stream>>>(x, user, item, xb2, tb2);

    hist_kernel<<<(N_EDGES + 255) / 256, 256, 0, stream>>>(col, cnt);
    scan_blk_kernel<<<NBLK_SCAN, 256, 0, stream>>>(cnt, offs_tmp, bsum);
    scan_top_kernel<<<1, 256, 0, stream>>>(bsum);
    scan_add_kernel<<<NBLK_SCAN, 256, 0, stream>>>(offs_tmp, bsum, offs, cnt);
    scatter_kernel<<<(N_EDGES + 255) / 256, 256, 0, stream>>>(row, col, cnt, esrc);

    const int gx = (N_NODES + 127) / 128;
    gemm_qkv_reg<<<dim3(gx, 6), 256, 0, stream>>>(tb2, xb2, Wb2, bq, bk, bv, Qb, KVb, N_NODES);

    node_fused_kernel<<<(N_NODES * 64 + 255) / 256, 256, 0, stream>>>(
        Qb, KVb, rel, offs, esrc, outagg2);

    gemm_o_reg<<<dim3(gx, 2), 256, 0, stream>>>(outagg2, Wb2, bo, (float*)d_out, N_NODES);
}